// Round 8
// baseline (996.615 us; speedup 1.0000x reference)
//
#include <hip/hip_runtime.h>
#include <cstdint>
#include <cstddef>

// SAMGuidedCrossAttention: B=4, C=256, H=W=256, heads=8, ws=8, d=32
//   prep_weights: wq/wk/wv/wp f32 -> bf16 in MFMA-FRAGMENT ORDER
//   qkv_gemm v8 = round-6 structure with the register clamp FIXED:
//     512-thr 2-PHASE PIPELINE. __launch_bounds__(512,2) (was (512,4) which
//     clamped VGPR to 64 -> total spill, r6's 1204us). Budget ~116 regs:
//     stage 8xfloat4=32, acc[4][2]=32, afr+naf=32, addr ~20.
//     Wave (ow=wid&3, nh=wid>>2): M=64 rows x N=32 cols.
//     Double-buffered 2x32KB LDS stage; issue(t+1) at tile top, pack->alt
//     after the K (or Q) pass; 1 barrier/tile Q, 2 KV.
//     Q-block = 2 image rows (8 tiles); KV-block = 1 row (4 tiles, K+V from
//     one xkv stage). V transpose wave-local in dead cur buffer (g-XOR swz).
//     Correctness of this exact structure verified in r6 (passed, absmax ok).
//   attn_conv: proven kernel (XCD-chunked winl swizzle, wpT fragment loads).

typedef __attribute__((ext_vector_type(8))) short bfx8;   // 8 bf16 (4 VGPR)
typedef __attribute__((ext_vector_type(4))) float f32x4;  // MFMA acc

#define HW 65536
#define NC 256
#define QKV_STRIDE 16777216UL  // ushorts per tensor per batch (1024*8*64*32)

__device__ __forceinline__ unsigned short f2bf(float f) {
  union { float f; unsigned u; } v; v.f = f;
  unsigned r = v.u + 0x7FFFu + ((v.u >> 16) & 1u);  // RNE
  return (unsigned short)(r >> 16);
}

// row-dependent XOR swizzle for the staged X tile (bits 4-6 of byte addr)
__device__ __forceinline__ unsigned xswz(unsigned n) {
  return ((n ^ (n >> 2)) & 7u) << 4;
}

// weights -> MFMA fragment order. dst[i]: i = ((o_tile*8+ks)*64+lane)*8+e
// holds w[o_tile*16 + (lane&15)][ks*32 + (lane>>4)*8 + e].
__global__ __launch_bounds__(256) void prep_weights(
    const float* __restrict__ wq, const float* __restrict__ wk,
    const float* __restrict__ wv, const float* __restrict__ wp,
    unsigned short* __restrict__ dst) {
  int i = blockIdx.x * 256 + threadIdx.x;  // grid 256 x 256 (65536 elements)
  int e = i & 7, lane = (i >> 3) & 63, ks = (i >> 9) & 7, ot = i >> 12;
  int src = (ot * 16 + (lane & 15)) * 256 + ks * 32 + (lane >> 4) * 8 + e;
  dst[i]          = f2bf(wq[src]);
  dst[i + 65536]  = f2bf(wk[src]);
  dst[i + 131072] = f2bf(wv[src]);
  dst[i + 196608] = f2bf(wp[src]);
}

// GEMM pass for 8-wave blocks: wave = M 64 rows (ow) x N 32 cols (nh).
__device__ __forceinline__ void gemm_pass8(
    const unsigned short* __restrict__ wT, const unsigned char* __restrict__ smem,
    int ow, int nh, int g, int qh, int lane, f32x4 (&acc)[4][2]) {
#pragma unroll
  for (int i = 0; i < 4; ++i) {
    acc[i][0] = (f32x4){0.f, 0.f, 0.f, 0.f};
    acc[i][1] = (f32x4){0.f, 0.f, 0.f, 0.f};
  }
  bfx8 afr[4];
#pragma unroll
  for (int mt = 0; mt < 4; ++mt)
    afr[mt] = *(const bfx8*)(wT + (((ow * 4 + mt) * 8 + 0) * 64 + lane) * 8);

  for (int ks = 0; ks < 8; ++ks) {
    bfx8 naf[4];
    if (ks < 7) {
#pragma unroll
      for (int mt = 0; mt < 4; ++mt)
        naf[mt] = *(const bfx8*)(wT + (((ow * 4 + mt) * 8 + ks + 1) * 64 + lane) * 8);
    }
#pragma unroll
    for (int nt = 0; nt < 2; ++nt) {
      unsigned n = (unsigned)(nh * 32 + nt * 16 + qh);
      bfx8 bfr = *(const bfx8*)(smem + ((n * 512 + (unsigned)(ks * 64 + g * 16)) ^ xswz(n)));
#pragma unroll
      for (int mt = 0; mt < 4; ++mt)
        acc[mt][nt] = __builtin_amdgcn_mfma_f32_16x16x32_bf16(afr[mt], bfr, acc[mt][nt], 0, 0, 0);
    }
    if (ks < 7) {
#pragma unroll
      for (int mt = 0; mt < 4; ++mt) afr[mt] = naf[mt];
    }
  }
}

// Direct windowed store for Q/K layout [win*8+head][pos 64][d 32] (+bias).
__device__ __forceinline__ void store_qk8(
    const f32x4 (&acc)[4][2], const float* __restrict__ bias,
    unsigned short* __restrict__ outw, int row, int w0b,
    int ow, int nh, int g, int qh) {
#pragma unroll
  for (int mt = 0; mt < 4; ++mt) {
    int o = ow * 64 + mt * 16 + g * 4;
    f32x4 bb = *(const f32x4*)&bias[o];
    int head = o >> 5, dbase = o & 31;
#pragma unroll
    for (int nt = 0; nt < 2; ++nt) {
      int pidx = nh * 32 + nt * 16 + qh;
      int w_img = w0b + pidx;
      int win = ((row >> 3) << 5) + (w_img >> 3);
      int pos = ((row & 7) << 3) + (w_img & 7);
      f32x4 a = acc[mt][nt];
      uint2 pv;
      pv.x = (unsigned)f2bf(a.x + bb.x) | ((unsigned)f2bf(a.y + bb.y) << 16);
      pv.y = (unsigned)f2bf(a.z + bb.z) | ((unsigned)f2bf(a.w + bb.w) << 16);
      *(uint2*)&outw[((size_t)(win * 8 + head) * 64 + pos) * 32 + dbase] = pv;
    }
  }
}

// ---------------- QKV projection GEMM (2-phase pipelined) ----------------
// grid (384, 1, NB), 512 thr (8 waves). idx<128: Q-block (2 rows, 8 tiles);
// idx>=128: KV-block (1 row, 4 tiles, K+V from one xkv stage).
__global__ __launch_bounds__(512, 2) void qkv_gemm(
    const float* __restrict__ xq, const float* __restrict__ xkv,
    const unsigned short* __restrict__ wbf,
    const float* __restrict__ bq, const float* __restrict__ bk,
    const float* __restrict__ bv,
    unsigned short* __restrict__ q_w, unsigned short* __restrict__ k_w,
    unsigned short* __restrict__ v_w, int batch0, int batched) {
  __shared__ __align__(16) unsigned char smem[2][32768];  // double-buffered stage

  const int tid = threadIdx.x;
  const int lane = tid & 63;
  const int wid = tid >> 6;        // 0..7
  const int g = lane >> 4;
  const int qh = lane & 15;
  const int ow = wid & 3;          // M-slice (64 rows)
  const int nh = wid >> 2;         // N-half (32 cols)

  const int idx = blockIdx.x;
  const int batch = batch0 + blockIdx.z;
  const size_t qofs = batched ? (size_t)blockIdx.z * QKV_STRIDE : 0;
  const bool isQ = idx < 128;
  const int nT = isQ ? 8 : 4;
  const float* x = (isQ ? xq : xkv) + (size_t)batch * NC * HW;

  // staging map: 16 threads -> pos quads, 32 channel-octets
  const int n4 = tid & 15;
  const int cgrp = tid >> 4;       // 0..31
  const float* xb = x + (size_t)(cgrp * 8) * HW + n4 * 4;

  f32x4 ld[8];  // in-flight x tile slice (32 VGPR)
  auto n0_of = [&](int t) {
    return isQ ? ((idx * 2 + (t >> 2)) * 256 + (t & 3) * 64)
               : ((idx - 128) * 256 + t * 64);
  };
  auto issue = [&](int t) {
    const int n0 = n0_of(t);
#pragma unroll
    for (int i = 0; i < 8; ++i) ld[i] = *(const f32x4*)(xb + (size_t)i * HW + n0);
  };
  auto pack = [&](unsigned char* dst) {
#pragma unroll
    for (int e = 0; e < 4; ++e) {
      unsigned n = (unsigned)(n4 * 4 + e);
      uint4 u;
      u.x = (unsigned)f2bf(ld[0][e]) | ((unsigned)f2bf(ld[1][e]) << 16);
      u.y = (unsigned)f2bf(ld[2][e]) | ((unsigned)f2bf(ld[3][e]) << 16);
      u.z = (unsigned)f2bf(ld[4][e]) | ((unsigned)f2bf(ld[5][e]) << 16);
      u.w = (unsigned)f2bf(ld[6][e]) | ((unsigned)f2bf(ld[7][e]) << 16);
      *(uint4*)(dst + ((n * 512 + (unsigned)cgrp * 16) ^ xswz(n))) = u;
    }
  };

  issue(0);
  pack(smem[0]);

  for (int t = 0; t < nT; ++t) {
    unsigned char* cur = smem[t & 1];
    unsigned char* alt = smem[(t + 1) & 1];
    __syncthreads();               // cur packed+visible; alt reads (t-1) done
    if (t + 1 < nT) issue(t + 1);  // next tile's loads fly under this GEMM
    const int n0 = n0_of(t);
    const int row = n0 >> 8, w0b = n0 & 255;

    if (isQ) {
      f32x4 acc[4][2];
      gemm_pass8(wbf, cur, ow, nh, g, qh, lane, acc);
      store_qk8(acc, bq, q_w + qofs, row, w0b, ow, nh, g, qh);
      if (t + 1 < nT) pack(alt);
    } else {
      f32x4 acc[4][2];
      gemm_pass8(wbf + 65536, cur, ow, nh, g, qh, lane, acc);      // wk
      store_qk8(acc, bk, k_w + qofs, row, w0b, ow, nh, g, qh);
      if (t + 1 < nT) pack(alt);   // ld dies here; V-pass runs reg-light
      f32x4 vacc[4][2];
      gemm_pass8(wbf + 131072, cur, ow, nh, g, qh, lane, vacc);    // wv
      __syncthreads();             // all cur reads done -> wave-local V-epi in cur
      char* vb_ = (char*)cur + wid * 4096;  // [64 loc][32 n] x 8 waves
#pragma unroll
      for (int mt = 0; mt < 4; ++mt) {
        int o = ow * 64 + mt * 16 + g * 4;
        f32x4 bb = *(const f32x4*)&bv[o];
        int loc0 = mt * 16 + g * 4;
        unsigned sw = (unsigned)g << 4;  // == ((loc>>2)&3)<<4 for these rows
#pragma unroll
        for (int nt = 0; nt < 2; ++nt) {
          int nl = nt * 16 + qh;
          f32x4 a = vacc[mt][nt];
          *(unsigned short*)(vb_ + ((unsigned)((loc0 + 0) * 64 + nl * 2) ^ sw)) = f2bf(a.x + bb.x);
          *(unsigned short*)(vb_ + ((unsigned)((loc0 + 1) * 64 + nl * 2) ^ sw)) = f2bf(a.y + bb.y);
          *(unsigned short*)(vb_ + ((unsigned)((loc0 + 2) * 64 + nl * 2) ^ sw)) = f2bf(a.z + bb.z);
          *(unsigned short*)(vb_ + ((unsigned)((loc0 + 3) * 64 + nl * 2) ^ sw)) = f2bf(a.w + bb.w);
        }
      }
      {
        int head = ow * 2 + (lane >> 5), dd = lane & 31;
        unsigned rsw = (unsigned)((lane >> 2) & 3) << 4;
        unsigned short* vw = v_w + qofs;
#pragma unroll
        for (int c = 0; c < 4; ++c) {
          uint4 val = *(const uint4*)(vb_ + ((unsigned)(lane * 64 + c * 16) ^ rsw));
          int w_img = w0b + nh * 32 + c * 8;
          int win = ((row >> 3) << 5) + (w_img >> 3);
          *(uint4*)&vw[((size_t)(win * 8 + head) * 32 + dd) * 64 + ((row & 7) << 3)] = val;
        }
      }
    }
  }
}

// ---------------- fused windowed attention + output conv ----------------
// Block: 256 thr (4 waves) = 1 window. Wave handles heads {wid, wid+4}.
__global__ __launch_bounds__(256) void attn_conv(
    const unsigned short* __restrict__ q_w, const unsigned short* __restrict__ k_w,
    const unsigned short* __restrict__ v_w, const unsigned short* __restrict__ wpT,
    const float* __restrict__ bp, float* __restrict__ out, int batch0, int batched) {
  __shared__ unsigned short P_lds[4][2048];  // per-wave P half-tile [64 q][32 k], swizzled
  __shared__ unsigned short y_t[16384];      // [pos 64][c 256] bf16, swizzled

  const int tid = threadIdx.x;
  const int lane = tid & 63;
  const int wid = tid >> 6;
  const int g = lane >> 4;
  const int qh = lane & 15;
  const int bid = blockIdx.x;
  // XCD-chunked swizzle: XCD j owns winl [j*128, +128).
  const int winl = ((bid & 7) << 7) | (bid >> 3);
  const int batch = batch0 + blockIdx.z;
  const size_t qofs = batched ? (size_t)blockIdx.z * QKV_STRIDE : 0;
  const float scale = 0.17677669529663687f;  // 1/sqrt(32)

  char* pbase = (char*)&P_lds[wid][0];

#pragma unroll
  for (int hi = 0; hi < 2; ++hi) {
    const int head = wid + hi * 4;
    const unsigned short* qb = q_w + qofs + (size_t)(winl * 8 + head) * 2048;
    const unsigned short* kb = k_w + qofs + (size_t)(winl * 8 + head) * 2048;
    const unsigned short* vb = v_w + qofs + (size_t)(winl * 8 + head) * 2048;

    bfx8 kf[4], qf[4];
#pragma unroll
    for (int t = 0; t < 4; ++t) {
      kf[t] = *(const bfx8*)(kb + (t * 16 + qh) * 32 + g * 8);
      qf[t] = *(const bfx8*)(qb + (t * 16 + qh) * 32 + g * 8);
    }
    // S^T[kpos][q] = sum_d K[kpos][d] * Q[q][d]
    f32x4 zero = {0.f, 0.f, 0.f, 0.f};
    f32x4 st[4][4];
#pragma unroll
    for (int kt = 0; kt < 4; ++kt)
#pragma unroll
      for (int qt = 0; qt < 4; ++qt)
        st[kt][qt] = __builtin_amdgcn_mfma_f32_16x16x32_bf16(kf[kt], qf[qt], zero, 0, 0, 0);

    // softmax over kpos (rows of S^T)
    float rv[4];
#pragma unroll
    for (int qt = 0; qt < 4; ++qt) {
      float m = -1e30f;
#pragma unroll
      for (int kt = 0; kt < 4; ++kt) {
        f32x4 v = st[kt][qt];
        m = fmaxf(m, fmaxf(fmaxf(v.x, v.y), fmaxf(v.z, v.w)));
      }
      m = fmaxf(m, __shfl_xor(m, 16, 64));
      m = fmaxf(m, __shfl_xor(m, 32, 64));
      float ssum = 0.f;
#pragma unroll
      for (int kt = 0; kt < 4; ++kt) {
        f32x4 v = st[kt][qt], e;
        e.x = __expf((v.x - m) * scale);
        e.y = __expf((v.y - m) * scale);
        e.z = __expf((v.z - m) * scale);
        e.w = __expf((v.w - m) * scale);
        ssum += e.x + e.y + e.z + e.w;
        st[kt][qt] = e;
      }
      ssum += __shfl_xor(ssum, 16, 64);
      ssum += __shfl_xor(ssum, 32, 64);
      rv[qt] = 1.f / ssum;
    }

    // PV: out^T[d][q] = sum_k V^T[d][k] * P
    f32x4 ot[2][4];
#pragma unroll
    for (int dt = 0; dt < 2; ++dt)
#pragma unroll
      for (int qt = 0; qt < 4; ++qt) ot[dt][qt] = zero;

#pragma unroll
    for (int s = 0; s < 2; ++s) {
#pragma unroll
      for (int qt = 0; qt < 4; ++qt) {
        int q = qt * 16 + qh;
        unsigned sw = ((unsigned)(q & 3)) << 4;
        float r = rv[qt];
#pragma unroll
        for (int k2 = 0; k2 < 2; ++k2) {
          f32x4 e = st[s * 2 + k2][qt];
          uint2 pv;
          pv.x = (unsigned)f2bf(e.x * r) | ((unsigned)f2bf(e.y * r) << 16);
          pv.y = (unsigned)f2bf(e.z * r) | ((unsigned)f2bf(e.w * r) << 16);
          unsigned byte = ((unsigned)q * 64 + (unsigned)(k2 * 32 + g * 8)) ^ sw;
          *(uint2*)(pbase + byte) = pv;
        }
      }
      bfx8 pf[4];
#pragma unroll
      for (int qt = 0; qt < 4; ++qt) {
        int q = qt * 16 + qh;
        unsigned byte = ((unsigned)q * 64 + (unsigned)(g * 16)) ^ (((unsigned)(q & 3)) << 4);
        pf[qt] = *(const bfx8*)(pbase + byte);
      }
#pragma unroll
      for (int dt = 0; dt < 2; ++dt) {
        bfx8 vf = *(const bfx8*)(vb + (dt * 16 + qh) * 64 + s * 32 + g * 8);
#pragma unroll
        for (int qt = 0; qt < 4; ++qt)
          ot[dt][qt] = __builtin_amdgcn_mfma_f32_16x16x32_bf16(vf, pf[qt], ot[dt][qt], 0, 0, 0);
      }
    }

    // attention output -> y_t[pos][c] (swizzled), c = head*32 + d
#pragma unroll
    for (int dt = 0; dt < 2; ++dt) {
      int cb = head * 32 + dt * 16 + g * 4;
#pragma unroll
      for (int qt = 0; qt < 4; ++qt) {
        int pos = qt * 16 + qh;
        f32x4 a = ot[dt][qt];
        uint2 pv;
        pv.x = (unsigned)f2bf(a.x) | ((unsigned)f2bf(a.y) << 16);
        pv.y = (unsigned)f2bf(a.z) | ((unsigned)f2bf(a.w) << 16);
        unsigned byte = ((unsigned)pos * 512 + (unsigned)cb * 2) ^ (((unsigned)(pos & 7)) << 4);
        *(uint2*)((char*)y_t + byte) = pv;
      }
    }
  }
  __syncthreads();

  // output conv: out[o][pos] = sum_c wp[o][c] * y[c][pos]; wave wid: o in [64*wid, +64)
  f32x4 acc[4][4];
#pragma unroll
  for (int i = 0; i < 4; ++i)
#pragma unroll
    for (int j = 0; j < 4; ++j) acc[i][j] = (f32x4){0.f, 0.f, 0.f, 0.f};

  for (int ks = 0; ks < 8; ++ks) {
    bfx8 af[4];
#pragma unroll
    for (int mt = 0; mt < 4; ++mt)
      af[mt] = *(const bfx8*)(wpT + (((wid * 4 + mt) * 8 + ks) * 64 + lane) * 8);
#pragma unroll
    for (int nt = 0; nt < 4; ++nt) {
      int pos = nt * 16 + qh;
      unsigned byte = ((unsigned)pos * 512 + (unsigned)(ks * 64 + g * 16)) ^ (((unsigned)(pos & 7)) << 4);
      bfx8 bfr = *(const bfx8*)((char*)y_t + byte);
#pragma unroll
      for (int mt = 0; mt < 4; ++mt)
        acc[mt][nt] = __builtin_amdgcn_mfma_f32_16x16x32_bf16(af[mt], bfr, acc[mt][nt], 0, 0, 0);
    }
  }

  const int wrow = winl >> 5, wcol = winl & 31;
  float* ob_ = out + (size_t)batch * NC * HW;
#pragma unroll
  for (int mt = 0; mt < 4; ++mt) {
    int o0 = wid * 64 + mt * 16 + g * 4;
    float b0 = bp[o0], b1 = bp[o0 + 1], b2 = bp[o0 + 2], b3 = bp[o0 + 3];
#pragma unroll
    for (int nt = 0; nt < 4; ++nt) {
      int pos = nt * 16 + qh;
      int h_img = wrow * 8 + (pos >> 3);
      int w_img = wcol * 8 + (pos & 7);
      float* pp = ob_ + (size_t)o0 * HW + h_img * 256 + w_img;
      pp[0]      = acc[mt][nt].x + b0;
      pp[HW]     = acc[mt][nt].y + b1;
      pp[2 * HW] = acc[mt][nt].z + b2;
      pp[3 * HW] = acc[mt][nt].w + b3;
    }
  }
}

extern "C" void kernel_launch(void* const* d_in, const int* in_sizes, int n_in,
                              void* d_out, int out_size, void* d_ws, size_t ws_size,
                              hipStream_t stream) {
  const float* q_feat = (const float*)d_in[0];
  const float* kv_feat = (const float*)d_in[1];
  const float* wq = (const float*)d_in[2];
  const float* bq = (const float*)d_in[3];
  const float* wk = (const float*)d_in[4];
  const float* bk = (const float*)d_in[5];
  const float* wv = (const float*)d_in[6];
  const float* bv = (const float*)d_in[7];
  const float* wp = (const float*)d_in[8];
  const float* bp = (const float*)d_in[9];
  float* out = (float*)d_out;

  unsigned short* wbf = (unsigned short*)d_ws;  // 4 x 65536 bf16 = 512 KB
  const size_t need_batched = 524288ul + 12ul * QKV_STRIDE * 2ul;  // ~403 MB

  hipLaunchKernelGGL(prep_weights, dim3(256), dim3(256), 0, stream, wq, wk, wv, wp, wbf);

  if (ws_size >= need_batched) {
    // all-batch path: 2 big launches, no inter-batch serialization bubbles
    unsigned short* q_w = wbf + 262144;
    unsigned short* k_w = q_w + 4 * QKV_STRIDE;
    unsigned short* v_w = k_w + 4 * QKV_STRIDE;
    hipLaunchKernelGGL(qkv_gemm, dim3(384, 1, 4), dim3(512), 0, stream,
                       q_feat, kv_feat, wbf, bq, bk, bv, q_w, k_w, v_w, 0, 1);
    hipLaunchKernelGGL(attn_conv, dim3(1024, 1, 4), dim3(256), 0, stream,
                       q_w, k_w, v_w, wbf + 196608, bp, out, 0, 1);
  } else {
    // per-batch fallback (~97 MB workspace)
    unsigned short* q_w = wbf + 262144;
    unsigned short* k_w = q_w + QKV_STRIDE;
    unsigned short* v_w = k_w + QKV_STRIDE;
    for (int b = 0; b < 4; ++b) {
      hipLaunchKernelGGL(qkv_gemm, dim3(384, 1, 1), dim3(512), 0, stream,
                         q_feat, kv_feat, wbf, bq, bk, bv, q_w, k_w, v_w, b, 0);
      hipLaunchKernelGGL(attn_conv, dim3(1024, 1, 1), dim3(256), 0, stream,
                         q_w, k_w, v_w, wbf + 196608, bp, out, b, 0);
    }
  }
}

// Round 9
// 743.930 us; speedup vs baseline: 1.3397x; 1.3397x over previous
//
#include <hip/hip_runtime.h>
#include <cstdint>
#include <cstddef>

// SAMGuidedCrossAttention: B=4, C=256, H=W=256, heads=8, ws=8, d=32
// Round 9 = proven round-2 qkv base + coalesced-store fixes:
//   qkv_gemm: Q/K epilogue via separate 36KB LDS epi buffer ->
//     [win][head][wq][d] (head-XOR swz) -> 64B-aligned uint4 store runs
//     (was 8B uint2 at 64B stride: ~64 sectors/instr). Mode1: K GEMM ->
//     K epi+store -> V GEMM -> V epi+store (one acc live; no spill).
//   attn_conv: block = 4 horizontally-adjacent windows (grid 256 x NB) so
//     the 4 windows sharing each 128B out line merge in L2 within one block.
//   prep_weights: wq/wk/wv row-order, wp fragment-order (r7 proven).

typedef __attribute__((ext_vector_type(8))) short bfx8;   // 8 bf16 (4 VGPR)
typedef __attribute__((ext_vector_type(4))) float f32x4;  // MFMA acc

#define HW 65536
#define NC 256
#define QKV_STRIDE 16777216UL  // ushorts per tensor per batch (1024*8*64*32)

__device__ __forceinline__ unsigned short f2bf(float f) {
  union { float f; unsigned u; } v; v.f = f;
  unsigned r = v.u + 0x7FFFu + ((v.u >> 16) & 1u);  // RNE
  return (unsigned short)(r >> 16);
}

__global__ __launch_bounds__(256) void prep_weights(
    const float* __restrict__ wq, const float* __restrict__ wk,
    const float* __restrict__ wv, const float* __restrict__ wp,
    unsigned short* __restrict__ dst) {
  int i = blockIdx.x * 256 + threadIdx.x;  // 65536 elements
  dst[i]          = f2bf(wq[i]);
  dst[i + 65536]  = f2bf(wk[i]);
  dst[i + 131072] = f2bf(wv[i]);
  int e = i & 7, lane = (i >> 3) & 63, ks = (i >> 9) & 7, ot = i >> 12;
  int src = (ot * 16 + (lane & 15)) * 256 + ks * 32 + (lane >> 4) * 8 + e;
  dst[i + 196608] = f2bf(wp[src]);
}

// round-2 staging: X[256 c][n0..n0+64) -> Xs[n][c] bf16, swz ((n&7)<<4)
__device__ __forceinline__ void stage_x(
    const float* __restrict__ x, int n0, int tid, unsigned char* __restrict__ smem) {
  const int sn = tid & 63;   // lane -> contiguous n (coalesced 256B/row)
  const int oc = tid >> 6;
#pragma unroll
  for (int it = 0; it < 8; ++it) {
    int c8 = (it * 4 + oc) * 8;
    const float* xp = x + (size_t)c8 * HW + n0 + sn;
    float v0 = xp[0],      v1 = xp[HW],     v2 = xp[2 * HW], v3 = xp[3 * HW];
    float v4 = xp[4 * HW], v5 = xp[5 * HW], v6 = xp[6 * HW], v7 = xp[7 * HW];
    uint4 u;
    u.x = (unsigned)f2bf(v0) | ((unsigned)f2bf(v1) << 16);
    u.y = (unsigned)f2bf(v2) | ((unsigned)f2bf(v3) << 16);
    u.z = (unsigned)f2bf(v4) | ((unsigned)f2bf(v5) << 16);
    u.w = (unsigned)f2bf(v6) | ((unsigned)f2bf(v7) << 16);
    unsigned byte = ((unsigned)(sn * 512 + c8 * 2)) ^ (((unsigned)(sn & 7)) << 4);
    *(uint4*)(smem + byte) = u;  // 16B write, conflict-free
  }
}

// round-2 GEMM pass: acc = W[256x256] * Xs. W row-order; Xs as staged above.
__device__ __forceinline__ void gemm_pass(
    const unsigned short* __restrict__ wmat, const unsigned char* __restrict__ smem,
    int wid, int g, int qh, f32x4 (&acc)[4][4]) {
#pragma unroll
  for (int i = 0; i < 4; ++i)
#pragma unroll
    for (int j = 0; j < 4; ++j) acc[i][j] = (f32x4){0.f, 0.f, 0.f, 0.f};

  bfx8 afr[4];
#pragma unroll
  for (int mt = 0; mt < 4; ++mt)
    afr[mt] = *(const bfx8*)(wmat + (wid * 64 + mt * 16 + qh) * 256 + g * 8);

  for (int ks = 0; ks < 8; ++ks) {
    bfx8 naf[4];
    if (ks < 7) {
#pragma unroll
      for (int mt = 0; mt < 4; ++mt)
        naf[mt] = *(const bfx8*)(wmat + (wid * 64 + mt * 16 + qh) * 256 + (ks + 1) * 32 + g * 8);
    }
#pragma unroll
    for (int nt = 0; nt < 4; ++nt) {
      unsigned byte = ((unsigned)((nt * 16 + qh) * 512 + ks * 64 + g * 16)) ^
                      (((unsigned)(qh & 7)) << 4);
      bfx8 bfr = *(const bfx8*)(smem + byte);
#pragma unroll
      for (int mt = 0; mt < 4; ++mt)
        acc[mt][nt] = __builtin_amdgcn_mfma_f32_16x16x32_bf16(afr[mt], bfr, acc[mt][nt], 0, 0, 0);
    }
    if (ks < 7) {
#pragma unroll
      for (int mt = 0; mt < 4; ++mt) afr[mt] = naf[mt];
    }
  }
}

// Q/K epilogue: acc -> LDS epi [win8][head8][wq8][d32] (head-XOR swz),
// then coalesced 64B uint4 store runs. Internal barrier before store reads.
__device__ __forceinline__ void epi_qk_store(
    const f32x4 (&acc)[4][4], const float* __restrict__ bias,
    unsigned short* __restrict__ outw, int n0, int wid, int g, int qh, int tid,
    unsigned char* __restrict__ epi) {
  const int h7 = (n0 >> 8) & 7;
  const int w0b = n0 & 255;
#pragma unroll
  for (int mt = 0; mt < 4; ++mt) {
    int o = wid * 64 + mt * 16 + g * 4;
    f32x4 bb = *(const f32x4*)&bias[o];
    int head = o >> 5, dbase = o & 31;
    unsigned hs = (unsigned)(head & 7) << 4;
#pragma unroll
    for (int nt = 0; nt < 4; ++nt) {
      int n = nt * 16 + qh;
      unsigned byte = ((unsigned)((n >> 3) * 4096 + head * 512 + (n & 7) * 64 + dbase * 2)) ^ hs;
      f32x4 a = acc[mt][nt];
      uint2 pv;
      pv.x = (unsigned)f2bf(a.x + bb.x) | ((unsigned)f2bf(a.y + bb.y) << 16);
      pv.y = (unsigned)f2bf(a.z + bb.z) | ((unsigned)f2bf(a.w + bb.w) << 16);
      *(uint2*)(epi + byte) = pv;
    }
  }
  __syncthreads();
  // store: run r = tid>>2 -> (winIdx = r>>3, head = r&7); 8 x uint4/thread
  const int r = tid >> 2, lane4 = tid & 3;
  const int winIdx = r >> 3, head = r & 7;
  const unsigned hs = (unsigned)(head & 7) << 4;
  const int win = ((n0 >> 8) >> 3) * 32 + (w0b >> 3) + winIdx;
  unsigned short* gdst = outw + (size_t)(win * 8 + head) * 2048 + h7 * 256;
  const unsigned char* src = epi + winIdx * 4096 + head * 512;
#pragma unroll
  for (int it = 0; it < 8; ++it) {
    unsigned off = (unsigned)(it * 64 + lane4 * 16);
    uint4 v = *(const uint4*)(src + (off ^ hs));
    *(uint4*)&gdst[it * 32 + lane4 * 8] = v;
  }
}

// ---------------- QKV projection GEMM ----------------
// grid (2048, 1, NB), 256 thr (4 waves). bid&1: 0 = Q, 1 = K+V (shared stage).
__global__ __launch_bounds__(256) void qkv_gemm(
    const float* __restrict__ xq, const float* __restrict__ xkv,
    const unsigned short* __restrict__ wbf,
    const float* __restrict__ bq, const float* __restrict__ bk,
    const float* __restrict__ bv,
    unsigned short* __restrict__ q_w, unsigned short* __restrict__ k_w,
    unsigned short* __restrict__ v_w, int batch0, int batched) {
  __shared__ __align__(16) unsigned char smem[32768];  // X stage
  __shared__ __align__(16) unsigned char epi[36864];   // Q/K epi 32KB | V epi 36KB

  const int tid = threadIdx.x;
  const int lane = tid & 63;
  const int wid = tid >> 6;
  const int g = lane >> 4;
  const int qh = lane & 15;
  const int mode = blockIdx.x & 1;
  const int n0 = (int)(blockIdx.x >> 1) * 64;
  const int batch = batch0 + blockIdx.z;
  const size_t qofs = batched ? (size_t)blockIdx.z * QKV_STRIDE : 0;
  const float* x = (mode ? xkv : xq) + (size_t)batch * NC * HW;

  stage_x(x, n0, tid, smem);
  __syncthreads();

  f32x4 acc[4][4];
  if (mode == 0) {
    gemm_pass(wbf, smem, wid, g, qh, acc);                 // wq
    epi_qk_store(acc, bq, q_w + qofs, n0, wid, g, qh, tid, epi);
  } else {
    gemm_pass(wbf + 65536, smem, wid, g, qh, acc);         // wk
    epi_qk_store(acc, bk, k_w + qofs, n0, wid, g, qh, tid, epi);
    gemm_pass(wbf + 131072, smem, wid, g, qh, acc);        // wv (stage reused)
    __syncthreads();  // K-store epi reads done -> V epi may overwrite
    unsigned short* Vt = (unsigned short*)epi;             // [o 256][n 64 pad 72]
#pragma unroll
    for (int mt = 0; mt < 4; ++mt) {
      int o = wid * 64 + mt * 16 + g * 4;
      f32x4 bb = *(const f32x4*)&bv[o];
#pragma unroll
      for (int nt = 0; nt < 4; ++nt) {
        int n = nt * 16 + qh;
        f32x4 a = acc[mt][nt];
        Vt[(o + 0) * 72 + n] = f2bf(a.x + bb.x);
        Vt[(o + 1) * 72 + n] = f2bf(a.y + bb.y);
        Vt[(o + 2) * 72 + n] = f2bf(a.z + bb.z);
        Vt[(o + 3) * 72 + n] = f2bf(a.w + bb.w);
      }
    }
    __syncthreads();
    const int h_img = n0 >> 8, w0b = n0 & 255;
    unsigned short* vw = v_w + qofs;
#pragma unroll
    for (int it = 0; it < 8; ++it) {
      int id = it * 256 + tid;
      int o = id >> 3, oct = id & 7;
      uint4 val = *(const uint4*)&Vt[o * 72 + oct * 8];
      int head = o >> 5, dd = o & 31;
      int win = ((h_img >> 3) << 5) + (w0b >> 3) + oct;
      *(uint4*)&vw[((size_t)(win * 8 + head) * 32 + dd) * 64 + ((h_img & 7) << 3)] = val;
    }
  }
}

// ---------------- fused windowed attention + output conv ----------------
// Block: 256 thr (4 waves) = 4 horizontally-adjacent windows, sequential.
// The 4 windows sharing each 128B out line are intra-block -> L2 merges.
__global__ __launch_bounds__(256) void attn_conv(
    const unsigned short* __restrict__ q_w, const unsigned short* __restrict__ k_w,
    const unsigned short* __restrict__ v_w, const unsigned short* __restrict__ wpT,
    const float* __restrict__ bp, float* __restrict__ out, int batch0, int batched) {
  __shared__ unsigned short P_lds[4][2048];  // per-wave P half-tile [64 q][32 k], swizzled
  __shared__ unsigned short y_t[16384];      // [pos 64][c 256] bf16, swizzled

  const int tid = threadIdx.x;
  const int lane = tid & 63;
  const int wid = tid >> 6;
  const int g = lane >> 4;
  const int qh = lane & 15;
  const int bid = blockIdx.x;                // 0..255
  const int wrow = bid >> 3;                 // 0..31
  const int wcol0 = (bid & 7) * 4;           // 4 consecutive window cols
  const int batch = batch0 + blockIdx.z;
  const size_t qofs = batched ? (size_t)blockIdx.z * QKV_STRIDE : 0;
  const float scale = 0.17677669529663687f;  // 1/sqrt(32)

  char* pbase = (char*)&P_lds[wid][0];
  float* ob_ = out + (size_t)batch * NC * HW;

  for (int wi = 0; wi < 4; ++wi) {
    if (wi) __syncthreads();  // prior window's conv reads of y_t done
    const int winl = wrow * 32 + wcol0 + wi;

#pragma unroll
    for (int hi = 0; hi < 2; ++hi) {
      const int head = wid + hi * 4;
      const unsigned short* qb = q_w + qofs + (size_t)(winl * 8 + head) * 2048;
      const unsigned short* kb = k_w + qofs + (size_t)(winl * 8 + head) * 2048;
      const unsigned short* vb = v_w + qofs + (size_t)(winl * 8 + head) * 2048;

      bfx8 kf[4], qf[4];
#pragma unroll
      for (int t = 0; t < 4; ++t) {
        kf[t] = *(const bfx8*)(kb + (t * 16 + qh) * 32 + g * 8);
        qf[t] = *(const bfx8*)(qb + (t * 16 + qh) * 32 + g * 8);
      }
      // S^T[kpos][q] = sum_d K[kpos][d] * Q[q][d]
      f32x4 zero = {0.f, 0.f, 0.f, 0.f};
      f32x4 st[4][4];
#pragma unroll
      for (int kt = 0; kt < 4; ++kt)
#pragma unroll
        for (int qt = 0; qt < 4; ++qt)
          st[kt][qt] = __builtin_amdgcn_mfma_f32_16x16x32_bf16(kf[kt], qf[qt], zero, 0, 0, 0);

      // softmax over kpos (rows of S^T)
      float rv[4];
#pragma unroll
      for (int qt = 0; qt < 4; ++qt) {
        float m = -1e30f;
#pragma unroll
        for (int kt = 0; kt < 4; ++kt) {
          f32x4 v = st[kt][qt];
          m = fmaxf(m, fmaxf(fmaxf(v.x, v.y), fmaxf(v.z, v.w)));
        }
        m = fmaxf(m, __shfl_xor(m, 16, 64));
        m = fmaxf(m, __shfl_xor(m, 32, 64));
        float ssum = 0.f;
#pragma unroll
        for (int kt = 0; kt < 4; ++kt) {
          f32x4 v = st[kt][qt], e;
          e.x = __expf((v.x - m) * scale);
          e.y = __expf((v.y - m) * scale);
          e.z = __expf((v.z - m) * scale);
          e.w = __expf((v.w - m) * scale);
          ssum += e.x + e.y + e.z + e.w;
          st[kt][qt] = e;
        }
        ssum += __shfl_xor(ssum, 16, 64);
        ssum += __shfl_xor(ssum, 32, 64);
        rv[qt] = 1.f / ssum;
      }

      // PV: out^T[d][q] = sum_k V^T[d][k] * P
      f32x4 ot[2][4];
#pragma unroll
      for (int dt = 0; dt < 2; ++dt)
#pragma unroll
        for (int qt = 0; qt < 4; ++qt) ot[dt][qt] = zero;

#pragma unroll
      for (int s = 0; s < 2; ++s) {
#pragma unroll
        for (int qt = 0; qt < 4; ++qt) {
          int q = qt * 16 + qh;
          unsigned sw = ((unsigned)(q & 3)) << 4;
          float r = rv[qt];
#pragma unroll
          for (int k2 = 0; k2 < 2; ++k2) {
            f32x4 e = st[s * 2 + k2][qt];
            uint2 pv;
            pv.x = (unsigned)f2bf(e.x * r) | ((unsigned)f2bf(e.y * r) << 16);
            pv.y = (unsigned)f2bf(e.z * r) | ((unsigned)f2bf(e.w * r) << 16);
            unsigned byte = ((unsigned)q * 64 + (unsigned)(k2 * 32 + g * 8)) ^ sw;
            *(uint2*)(pbase + byte) = pv;
          }
        }
        bfx8 pf[4];
#pragma unroll
        for (int qt = 0; qt < 4; ++qt) {
          int q = qt * 16 + qh;
          unsigned byte = ((unsigned)q * 64 + (unsigned)(g * 16)) ^ (((unsigned)(q & 3)) << 4);
          pf[qt] = *(const bfx8*)(pbase + byte);
        }
#pragma unroll
        for (int dt = 0; dt < 2; ++dt) {
          bfx8 vf = *(const bfx8*)(vb + (dt * 16 + qh) * 64 + s * 32 + g * 8);
#pragma unroll
          for (int qt = 0; qt < 4; ++qt)
            ot[dt][qt] = __builtin_amdgcn_mfma_f32_16x16x32_bf16(vf, pf[qt], ot[dt][qt], 0, 0, 0);
        }
      }

      // attention output -> y_t[pos][c] (swizzled), c = head*32 + d
#pragma unroll
      for (int dt = 0; dt < 2; ++dt) {
        int cb = head * 32 + dt * 16 + g * 4;
#pragma unroll
        for (int qt = 0; qt < 4; ++qt) {
          int pos = qt * 16 + qh;
          f32x4 a = ot[dt][qt];
          uint2 pv;
          pv.x = (unsigned)f2bf(a.x) | ((unsigned)f2bf(a.y) << 16);
          pv.y = (unsigned)f2bf(a.z) | ((unsigned)f2bf(a.w) << 16);
          unsigned byte = ((unsigned)pos * 512 + (unsigned)cb * 2) ^ (((unsigned)(pos & 7)) << 4);
          *(uint2*)((char*)y_t + byte) = pv;
        }
      }
    }
    __syncthreads();

    // output conv: out[o][pos] = sum_c wp[o][c]*y[c][pos]; wave: o in [64wid,+64)
    f32x4 acc[4][4];
#pragma unroll
    for (int i = 0; i < 4; ++i)
#pragma unroll
      for (int j = 0; j < 4; ++j) acc[i][j] = (f32x4){0.f, 0.f, 0.f, 0.f};

    for (int ks = 0; ks < 8; ++ks) {
      bfx8 af[4];
#pragma unroll
      for (int mt = 0; mt < 4; ++mt)
        af[mt] = *(const bfx8*)(wpT + (((wid * 4 + mt) * 8 + ks) * 64 + lane) * 8);
#pragma unroll
      for (int nt = 0; nt < 4; ++nt) {
        int pos = nt * 16 + qh;
        unsigned byte = ((unsigned)pos * 512 + (unsigned)(ks * 64 + g * 16)) ^ (((unsigned)(pos & 7)) << 4);
        bfx8 bfr = *(const bfx8*)((char*)y_t + byte);
#pragma unroll
        for (int mt = 0; mt < 4; ++mt)
          acc[mt][nt] = __builtin_amdgcn_mfma_f32_16x16x32_bf16(af[mt], bfr, acc[mt][nt], 0, 0, 0);
      }
    }

    const int wcol = wcol0 + wi;
#pragma unroll
    for (int mt = 0; mt < 4; ++mt) {
      int o0 = wid * 64 + mt * 16 + g * 4;
      float b0 = bp[o0], b1 = bp[o0 + 1], b2 = bp[o0 + 2], b3 = bp[o0 + 3];
#pragma unroll
      for (int nt = 0; nt < 4; ++nt) {
        int pos = nt * 16 + qh;
        int h_img = wrow * 8 + (pos >> 3);
        int w_img = wcol * 8 + (pos & 7);
        float* pp = ob_ + (size_t)o0 * HW + h_img * 256 + w_img;
        pp[0]      = acc[mt][nt].x + b0;
        pp[HW]     = acc[mt][nt].y + b1;
        pp[2 * HW] = acc[mt][nt].z + b2;
        pp[3 * HW] = acc[mt][nt].w + b3;
      }
    }
  }  // window loop
}

extern "C" void kernel_launch(void* const* d_in, const int* in_sizes, int n_in,
                              void* d_out, int out_size, void* d_ws, size_t ws_size,
                              hipStream_t stream) {
  const float* q_feat = (const float*)d_in[0];
  const float* kv_feat = (const float*)d_in[1];
  const float* wq = (const float*)d_in[2];
  const float* bq = (const float*)d_in[3];
  const float* wk = (const float*)d_in[4];
  const float* bk = (const float*)d_in[5];
  const float* wv = (const float*)d_in[6];
  const float* bv = (const float*)d_in[7];
  const float* wp = (const float*)d_in[8];
  const float* bp = (const float*)d_in[9];
  float* out = (float*)d_out;

  unsigned short* wbf = (unsigned short*)d_ws;  // 4 x 65536 bf16 = 512 KB
  const size_t need_batched = 524288ul + 12ul * QKV_STRIDE * 2ul;  // ~403 MB

  hipLaunchKernelGGL(prep_weights, dim3(256), dim3(256), 0, stream, wq, wk, wv, wp, wbf);

  if (ws_size >= need_batched) {
    // all-batch path: 2 big launches
    unsigned short* q_w = wbf + 262144;
    unsigned short* k_w = q_w + 4 * QKV_STRIDE;
    unsigned short* v_w = k_w + 4 * QKV_STRIDE;
    hipLaunchKernelGGL(qkv_gemm, dim3(2048, 1, 4), dim3(256), 0, stream,
                       q_feat, kv_feat, wbf, bq, bk, bv, q_w, k_w, v_w, 0, 1);
    hipLaunchKernelGGL(attn_conv, dim3(256, 1, 4), dim3(256), 0, stream,
                       q_w, k_w, v_w, wbf + 196608, bp, out, 0, 1);
  } else {
    // per-batch fallback (~97 MB workspace)
    unsigned short* q_w = wbf + 262144;
    unsigned short* k_w = q_w + QKV_STRIDE;
    unsigned short* v_w = k_w + QKV_STRIDE;
    for (int b = 0; b < 4; ++b) {
      hipLaunchKernelGGL(qkv_gemm, dim3(2048, 1, 1), dim3(256), 0, stream,
                         q_feat, kv_feat, wbf, bq, bk, bv, q_w, k_w, v_w, b, 0);
      hipLaunchKernelGGL(attn_conv, dim3(256, 1, 1), dim3(256), 0, stream,
                         q_w, k_w, v_w, wbf + 196608, bp, out, b, 0);
    }
  }
}

// Round 10
// 605.394 us; speedup vs baseline: 1.6462x; 1.2288x over previous
//
#include <hip/hip_runtime.h>
#include <cstdint>
#include <cstddef>

// SAMGuidedCrossAttention: B=4, C=256, H=W=256, heads=8, ws=8, d=32
// Round 10: FUSED-QKV blocks + proven r2 attn.
//   qkv_gemm: ONE block per 64-pos tile does Q AND K AND V:
//     stage xq->buf0, xkv->buf1 back-to-back (128 loads in flight, one
//     barrier), then 3 GEMM passes + 3 epilogues. Halves stage phases and
//     dispatch slots per unit work vs the r2 two-block split. V epilogue
//     transposes into the dead buf0 with swizzle ^(((o>>2)&7)<<4) on an
//     [o 256][n 64] 128B-stride layout (2-way max = free; r9's conflict
//     lesson: swizzle term must vary with the in-instruction lane dim).
//   attn_conv: r2-proven exact (1 window/block, XCD-chunked winl swizzle,
//     wpT fragment A-loads).
//   prep_weights: wq/wk/wv row order, wp fragment order.

typedef __attribute__((ext_vector_type(8))) short bfx8;   // 8 bf16 (4 VGPR)
typedef __attribute__((ext_vector_type(4))) float f32x4;  // MFMA acc

#define HW 65536
#define NC 256
#define QKV_STRIDE 16777216UL  // ushorts per tensor per batch (1024*8*64*32)

__device__ __forceinline__ unsigned short f2bf(float f) {
  union { float f; unsigned u; } v; v.f = f;
  unsigned r = v.u + 0x7FFFu + ((v.u >> 16) & 1u);  // RNE
  return (unsigned short)(r >> 16);
}

__global__ __launch_bounds__(256) void prep_weights(
    const float* __restrict__ wq, const float* __restrict__ wk,
    const float* __restrict__ wv, const float* __restrict__ wp,
    unsigned short* __restrict__ dst) {
  int i = blockIdx.x * 256 + threadIdx.x;  // 65536 elements
  dst[i]          = f2bf(wq[i]);
  dst[i + 65536]  = f2bf(wk[i]);
  dst[i + 131072] = f2bf(wv[i]);
  int e = i & 7, lane = (i >> 3) & 63, ks = (i >> 9) & 7, ot = i >> 12;
  int src = (ot * 16 + (lane & 15)) * 256 + ks * 32 + (lane >> 4) * 8 + e;
  dst[i + 196608] = f2bf(wp[src]);
}

// r2 staging: X[256 c][n0..n0+64) -> Xs[n][c] bf16, swz ((n&7)<<4)
__device__ __forceinline__ void stage_x(
    const float* __restrict__ x, int n0, int tid, unsigned char* __restrict__ smem) {
  const int sn = tid & 63;   // lane -> contiguous n (coalesced 256B/row)
  const int oc = tid >> 6;
#pragma unroll
  for (int it = 0; it < 8; ++it) {
    int c8 = (it * 4 + oc) * 8;
    const float* xp = x + (size_t)c8 * HW + n0 + sn;
    float v0 = xp[0],      v1 = xp[HW],     v2 = xp[2 * HW], v3 = xp[3 * HW];
    float v4 = xp[4 * HW], v5 = xp[5 * HW], v6 = xp[6 * HW], v7 = xp[7 * HW];
    uint4 u;
    u.x = (unsigned)f2bf(v0) | ((unsigned)f2bf(v1) << 16);
    u.y = (unsigned)f2bf(v2) | ((unsigned)f2bf(v3) << 16);
    u.z = (unsigned)f2bf(v4) | ((unsigned)f2bf(v5) << 16);
    u.w = (unsigned)f2bf(v6) | ((unsigned)f2bf(v7) << 16);
    unsigned byte = ((unsigned)(sn * 512 + c8 * 2)) ^ (((unsigned)(sn & 7)) << 4);
    *(uint4*)(smem + byte) = u;  // 16B write, conflict-free
  }
}

// r2 GEMM pass: acc = W[256x256] * Xs. W row-order; Xs as staged above.
__device__ __forceinline__ void gemm_pass(
    const unsigned short* __restrict__ wmat, const unsigned char* __restrict__ smem,
    int wid, int g, int qh, f32x4 (&acc)[4][4]) {
#pragma unroll
  for (int i = 0; i < 4; ++i)
#pragma unroll
    for (int j = 0; j < 4; ++j) acc[i][j] = (f32x4){0.f, 0.f, 0.f, 0.f};

  bfx8 afr[4];
#pragma unroll
  for (int mt = 0; mt < 4; ++mt)
    afr[mt] = *(const bfx8*)(wmat + (wid * 64 + mt * 16 + qh) * 256 + g * 8);

  for (int ks = 0; ks < 8; ++ks) {
    bfx8 naf[4];
    if (ks < 7) {
#pragma unroll
      for (int mt = 0; mt < 4; ++mt)
        naf[mt] = *(const bfx8*)(wmat + (wid * 64 + mt * 16 + qh) * 256 + (ks + 1) * 32 + g * 8);
    }
#pragma unroll
    for (int nt = 0; nt < 4; ++nt) {
      unsigned byte = ((unsigned)((nt * 16 + qh) * 512 + ks * 64 + g * 16)) ^
                      (((unsigned)(qh & 7)) << 4);
      bfx8 bfr = *(const bfx8*)(smem + byte);
#pragma unroll
      for (int mt = 0; mt < 4; ++mt)
        acc[mt][nt] = __builtin_amdgcn_mfma_f32_16x16x32_bf16(afr[mt], bfr, acc[mt][nt], 0, 0, 0);
    }
    if (ks < 7) {
#pragma unroll
      for (int mt = 0; mt < 4; ++mt) afr[mt] = naf[mt];
    }
  }
}

// Direct windowed store for Q/K layout [win*8+head][pos 64][d 32] (+bias).
__device__ __forceinline__ void store_qk(
    const f32x4 (&acc)[4][4], const float* __restrict__ bias,
    unsigned short* __restrict__ outw, int n0, int wid, int g, int qh) {
  const int h_img = n0 >> 8, w0b = n0 & 255;
#pragma unroll
  for (int mt = 0; mt < 4; ++mt) {
    int o = wid * 64 + mt * 16 + g * 4;
    f32x4 bb = *(const f32x4*)&bias[o];
    int head = o >> 5, dbase = o & 31;
#pragma unroll
    for (int nt = 0; nt < 4; ++nt) {
      int n = nt * 16 + qh;
      int w_img = w0b + n;
      int win = ((h_img >> 3) << 5) + (w_img >> 3);
      int pos = ((h_img & 7) << 3) + (w_img & 7);
      f32x4 a = acc[mt][nt];
      uint2 pv;
      pv.x = (unsigned)f2bf(a.x + bb.x) | ((unsigned)f2bf(a.y + bb.y) << 16);
      pv.y = (unsigned)f2bf(a.z + bb.z) | ((unsigned)f2bf(a.w + bb.w) << 16);
      *(uint2*)&outw[((size_t)(win * 8 + head) * 64 + pos) * 32 + dbase] = pv;
    }
  }
}

// ---------------- fused QKV projection GEMM ----------------
// grid (1024, 1, NB), 256 thr (4 waves). Block = one 64-pos tile, Q+K+V.
__global__ __launch_bounds__(256) void qkv_gemm(
    const float* __restrict__ xq, const float* __restrict__ xkv,
    const unsigned short* __restrict__ wbf,
    const float* __restrict__ bq, const float* __restrict__ bk,
    const float* __restrict__ bv,
    unsigned short* __restrict__ q_w, unsigned short* __restrict__ k_w,
    unsigned short* __restrict__ v_w, int batch0, int batched) {
  __shared__ __align__(16) unsigned char bufQ[32768];   // xq stage | V-epi
  __shared__ __align__(16) unsigned char bufKV[32768];  // xkv stage (K and V)

  const int tid = threadIdx.x;
  const int lane = tid & 63;
  const int wid = tid >> 6;
  const int g = lane >> 4;
  const int qh = lane & 15;
  const int n0 = (int)blockIdx.x * 64;
  const int batch = batch0 + blockIdx.z;
  const size_t qofs = batched ? (size_t)blockIdx.z * QKV_STRIDE : 0;
  const float* xq_b = xq + (size_t)batch * NC * HW;
  const float* xkv_b = xkv + (size_t)batch * NC * HW;

  // stage BOTH tensors: 128 loads in flight, one barrier
  stage_x(xq_b, n0, tid, bufQ);
  stage_x(xkv_b, n0, tid, bufKV);
  __syncthreads();

  f32x4 acc[4][4];
  gemm_pass(wbf, bufQ, wid, g, qh, acc);                 // wq
  store_qk(acc, bq, q_w + qofs, n0, wid, g, qh);
  gemm_pass(wbf + 65536, bufKV, wid, g, qh, acc);        // wk
  store_qk(acc, bk, k_w + qofs, n0, wid, g, qh);
  gemm_pass(wbf + 131072, bufKV, wid, g, qh, acc);       // wv

  __syncthreads();  // all LDS reads (incl. bufQ from Q pass) done
  // V epilogue transpose into bufQ: [o 256][n 64] bf16 (128B rows),
  // byte = o*128 + n*2 ^ (((o>>2)&7)<<4). Write conflicts <= 2-way (free).
#pragma unroll
  for (int mt = 0; mt < 4; ++mt) {
    int o = wid * 64 + mt * 16 + g * 4;
    f32x4 bb = *(const f32x4*)&bv[o];
#pragma unroll
    for (int nt = 0; nt < 4; ++nt) {
      int n = nt * 16 + qh;
      f32x4 a = acc[mt][nt];
      float vj[4] = {a.x + bb.x, a.y + bb.y, a.z + bb.z, a.w + bb.w};
#pragma unroll
      for (int j = 0; j < 4; ++j) {
        unsigned oo = (unsigned)(o + j);
        unsigned byte = (oo * 128 + (unsigned)n * 2) ^ (((oo >> 2) & 7u) << 4);
        *(unsigned short*)(bufQ + byte) = f2bf(vj[j]);
      }
    }
  }
  __syncthreads();
  // V store: [win*8+head][d 32][pos 64]
  const int h_img = n0 >> 8, w0b = n0 & 255;
  unsigned short* vw = v_w + qofs;
#pragma unroll
  for (int it = 0; it < 8; ++it) {
    int id = it * 256 + tid;
    unsigned o = (unsigned)(id >> 3);
    int oct = id & 7;
    unsigned byte = (o * 128 + (unsigned)oct * 16) ^ (((o >> 2) & 7u) << 4);
    uint4 val = *(const uint4*)(bufQ + byte);
    int head = (int)(o >> 5), dd = (int)(o & 31);
    int win = ((h_img >> 3) << 5) + (w0b >> 3) + oct;
    *(uint4*)&vw[((size_t)(win * 8 + head) * 32 + dd) * 64 + ((h_img & 7) << 3)] = val;
  }
}

// ---------------- fused windowed attention + output conv (r2 proven) ----------
// Block: 256 thr (4 waves) = 1 window. Wave handles heads {wid, wid+4}.
__global__ __launch_bounds__(256) void attn_conv(
    const unsigned short* __restrict__ q_w, const unsigned short* __restrict__ k_w,
    const unsigned short* __restrict__ v_w, const unsigned short* __restrict__ wpT,
    const float* __restrict__ bp, float* __restrict__ out, int batch0, int batched) {
  __shared__ unsigned short P_lds[4][2048];  // per-wave P half-tile [64 q][32 k], swizzled
  __shared__ unsigned short y_t[16384];      // [pos 64][c 256] bf16, swizzled

  const int tid = threadIdx.x;
  const int lane = tid & 63;
  const int wid = tid >> 6;
  const int g = lane >> 4;
  const int qh = lane & 15;
  const int bid = blockIdx.x;
  // XCD-chunked swizzle: XCD j owns winl [j*128, +128).
  const int winl = ((bid & 7) << 7) | (bid >> 3);
  const int batch = batch0 + blockIdx.z;
  const size_t qofs = batched ? (size_t)blockIdx.z * QKV_STRIDE : 0;
  const float scale = 0.17677669529663687f;  // 1/sqrt(32)

  char* pbase = (char*)&P_lds[wid][0];

#pragma unroll
  for (int hi = 0; hi < 2; ++hi) {
    const int head = wid + hi * 4;
    const unsigned short* qb = q_w + qofs + (size_t)(winl * 8 + head) * 2048;
    const unsigned short* kb = k_w + qofs + (size_t)(winl * 8 + head) * 2048;
    const unsigned short* vb = v_w + qofs + (size_t)(winl * 8 + head) * 2048;

    bfx8 kf[4], qf[4];
#pragma unroll
    for (int t = 0; t < 4; ++t) {
      kf[t] = *(const bfx8*)(kb + (t * 16 + qh) * 32 + g * 8);
      qf[t] = *(const bfx8*)(qb + (t * 16 + qh) * 32 + g * 8);
    }
    // S^T[kpos][q] = sum_d K[kpos][d] * Q[q][d]
    f32x4 zero = {0.f, 0.f, 0.f, 0.f};
    f32x4 st[4][4];
#pragma unroll
    for (int kt = 0; kt < 4; ++kt)
#pragma unroll
      for (int qt = 0; qt < 4; ++qt)
        st[kt][qt] = __builtin_amdgcn_mfma_f32_16x16x32_bf16(kf[kt], qf[qt], zero, 0, 0, 0);

    // softmax over kpos (rows of S^T)
    float rv[4];
#pragma unroll
    for (int qt = 0; qt < 4; ++qt) {
      float m = -1e30f;
#pragma unroll
      for (int kt = 0; kt < 4; ++kt) {
        f32x4 v = st[kt][qt];
        m = fmaxf(m, fmaxf(fmaxf(v.x, v.y), fmaxf(v.z, v.w)));
      }
      m = fmaxf(m, __shfl_xor(m, 16, 64));
      m = fmaxf(m, __shfl_xor(m, 32, 64));
      float ssum = 0.f;
#pragma unroll
      for (int kt = 0; kt < 4; ++kt) {
        f32x4 v = st[kt][qt], e;
        e.x = __expf((v.x - m) * scale);
        e.y = __expf((v.y - m) * scale);
        e.z = __expf((v.z - m) * scale);
        e.w = __expf((v.w - m) * scale);
        ssum += e.x + e.y + e.z + e.w;
        st[kt][qt] = e;
      }
      ssum += __shfl_xor(ssum, 16, 64);
      ssum += __shfl_xor(ssum, 32, 64);
      rv[qt] = 1.f / ssum;
    }

    // PV: out^T[d][q] = sum_k V^T[d][k] * P
    f32x4 ot[2][4];
#pragma unroll
    for (int dt = 0; dt < 2; ++dt)
#pragma unroll
      for (int qt = 0; qt < 4; ++qt) ot[dt][qt] = zero;

#pragma unroll
    for (int s = 0; s < 2; ++s) {
#pragma unroll
      for (int qt = 0; qt < 4; ++qt) {
        int q = qt * 16 + qh;
        unsigned sw = ((unsigned)(q & 3)) << 4;
        float r = rv[qt];
#pragma unroll
        for (int k2 = 0; k2 < 2; ++k2) {
          f32x4 e = st[s * 2 + k2][qt];
          uint2 pv;
          pv.x = (unsigned)f2bf(e.x * r) | ((unsigned)f2bf(e.y * r) << 16);
          pv.y = (unsigned)f2bf(e.z * r) | ((unsigned)f2bf(e.w * r) << 16);
          unsigned byte = ((unsigned)q * 64 + (unsigned)(k2 * 32 + g * 8)) ^ sw;
          *(uint2*)(pbase + byte) = pv;
        }
      }
      bfx8 pf[4];
#pragma unroll
      for (int qt = 0; qt < 4; ++qt) {
        int q = qt * 16 + qh;
        unsigned byte = ((unsigned)q * 64 + (unsigned)(g * 16)) ^ (((unsigned)(q & 3)) << 4);
        pf[qt] = *(const bfx8*)(pbase + byte);
      }
#pragma unroll
      for (int dt = 0; dt < 2; ++dt) {
        bfx8 vf = *(const bfx8*)(vb + (dt * 16 + qh) * 64 + s * 32 + g * 8);
#pragma unroll
        for (int qt = 0; qt < 4; ++qt)
          ot[dt][qt] = __builtin_amdgcn_mfma_f32_16x16x32_bf16(vf, pf[qt], ot[dt][qt], 0, 0, 0);
      }
    }

    // attention output -> y_t[pos][c] (swizzled), c = head*32 + d
#pragma unroll
    for (int dt = 0; dt < 2; ++dt) {
      int cb = head * 32 + dt * 16 + g * 4;
#pragma unroll
      for (int qt = 0; qt < 4; ++qt) {
        int pos = qt * 16 + qh;
        f32x4 a = ot[dt][qt];
        uint2 pv;
        pv.x = (unsigned)f2bf(a.x) | ((unsigned)f2bf(a.y) << 16);
        pv.y = (unsigned)f2bf(a.z) | ((unsigned)f2bf(a.w) << 16);
        unsigned byte = ((unsigned)pos * 512 + (unsigned)cb * 2) ^ (((unsigned)(pos & 7)) << 4);
        *(uint2*)((char*)y_t + byte) = pv;
      }
    }
  }
  __syncthreads();

  // output conv: out[o][pos] = sum_c wp[o][c] * y[c][pos]; wave wid: o in [64*wid, +64)
  f32x4 acc[4][4];
#pragma unroll
  for (int i = 0; i < 4; ++i)
#pragma unroll
    for (int j = 0; j < 4; ++j) acc[i][j] = (f32x4){0.f, 0.f, 0.f, 0.f};

  for (int ks = 0; ks < 8; ++ks) {
    bfx8 af[4];
#pragma unroll
    for (int mt = 0; mt < 4; ++mt)
      af[mt] = *(const bfx8*)(wpT + (((wid * 4 + mt) * 8 + ks) * 64 + lane) * 8);
#pragma unroll
    for (int nt = 0; nt < 4; ++nt) {
      int pos = nt * 16 + qh;
      unsigned byte = ((unsigned)pos * 512 + (unsigned)(ks * 64 + g * 16)) ^ (((unsigned)(pos & 7)) << 4);
      bfx8 bfr = *(const bfx8*)((char*)y_t + byte);
#pragma unroll
      for (int mt = 0; mt < 4; ++mt)
        acc[mt][nt] = __builtin_amdgcn_mfma_f32_16x16x32_bf16(af[mt], bfr, acc[mt][nt], 0, 0, 0);
    }
  }

  const int wrow = winl >> 5, wcol = winl & 31;
  float* ob_ = out + (size_t)batch * NC * HW;
#pragma unroll
  for (int mt = 0; mt < 4; ++mt) {
    int o0 = wid * 64 + mt * 16 + g * 4;
    float b0 = bp[o0], b1 = bp[o0 + 1], b2 = bp[o0 + 2], b3 = bp[o0 + 3];
#pragma unroll
    for (int nt = 0; nt < 4; ++nt) {
      int pos = nt * 16 + qh;
      int h_img = wrow * 8 + (pos >> 3);
      int w_img = wcol * 8 + (pos & 7);
      float* pp = ob_ + (size_t)o0 * HW + h_img * 256 + w_img;
      pp[0]      = acc[mt][nt].x + b0;
      pp[HW]     = acc[mt][nt].y + b1;
      pp[2 * HW] = acc[mt][nt].z + b2;
      pp[3 * HW] = acc[mt][nt].w + b3;
    }
  }
}

extern "C" void kernel_launch(void* const* d_in, const int* in_sizes, int n_in,
                              void* d_out, int out_size, void* d_ws, size_t ws_size,
                              hipStream_t stream) {
  const float* q_feat = (const float*)d_in[0];
  const float* kv_feat = (const float*)d_in[1];
  const float* wq = (const float*)d_in[2];
  const float* bq = (const float*)d_in[3];
  const float* wk = (const float*)d_in[4];
  const float* bk = (const float*)d_in[5];
  const float* wv = (const float*)d_in[6];
  const float* bv = (const float*)d_in[7];
  const float* wp = (const float*)d_in[8];
  const float* bp = (const float*)d_in[9];
  float* out = (float*)d_out;

  unsigned short* wbf = (unsigned short*)d_ws;  // 4 x 65536 bf16 = 512 KB
  const size_t need_batched = 524288ul + 12ul * QKV_STRIDE * 2ul;  // ~403 MB

  hipLaunchKernelGGL(prep_weights, dim3(256), dim3(256), 0, stream, wq, wk, wv, wp, wbf);

  if (ws_size >= need_batched) {
    // all-batch path: 2 big launches
    unsigned short* q_w = wbf + 262144;
    unsigned short* k_w = q_w + 4 * QKV_STRIDE;
    unsigned short* v_w = k_w + 4 * QKV_STRIDE;
    hipLaunchKernelGGL(qkv_gemm, dim3(1024, 1, 4), dim3(256), 0, stream,
                       q_feat, kv_feat, wbf, bq, bk, bv, q_w, k_w, v_w, 0, 1);
    hipLaunchKernelGGL(attn_conv, dim3(1024, 1, 4), dim3(256), 0, stream,
                       q_w, k_w, v_w, wbf + 196608, bp, out, 0, 1);
  } else {
    // per-batch fallback (~97 MB workspace)
    unsigned short* q_w = wbf + 262144;
    unsigned short* k_w = q_w + QKV_STRIDE;
    unsigned short* v_w = k_w + QKV_STRIDE;
    for (int b = 0; b < 4; ++b) {
      hipLaunchKernelGGL(qkv_gemm, dim3(1024, 1, 1), dim3(256), 0, stream,
                         q_feat, kv_feat, wbf, bq, bk, bv, q_w, k_w, v_w, b, 0);
      hipLaunchKernelGGL(attn_conv, dim3(1024, 1, 1), dim3(256), 0, stream,
                         q_w, k_w, v_w, wbf + 196608, bp, out, b, 0);
    }
  }
}

// Round 11
// 563.684 us; speedup vs baseline: 1.7680x; 1.0740x over previous
//
#include <hip/hip_runtime.h>
#include <cstdint>
#include <cstddef>

// SAMGuidedCrossAttention: B=4, C=256, H=W=256, heads=8, ws=8, d=32
// Round 11 = r10 fused-QKV base + FULL-LINE V LAYOUT:
//   V stored as [win*8+head][rowblk 8][d 32][col 8] (was [..][d][pos 64]).
//   A qkv block owns exactly one rowblk of each window -> its V store is
//   512B contiguous per (win,head): 8x128B full lines per instruction,
//   no cross-block line assembly (was 16B chunks at 128B stride from 8
//   blocks -> 2.2x write amplification, the r10 WRITE=558MB vs 400 ideal).
//   attn reads vf = vb[(s*4+g)*256 + d*8]: still contiguous bfx8, and
//   lane-contiguous 256B runs (better than old 128B-stride).
//   qkv_gemm: one block per 64-pos tile does Q+K+V off one staged barrier.
//   attn_conv: r2-proven (1 window/block, XCD-chunked winl swizzle, wpT).

typedef __attribute__((ext_vector_type(8))) short bfx8;   // 8 bf16 (4 VGPR)
typedef __attribute__((ext_vector_type(4))) float f32x4;  // MFMA acc

#define HW 65536
#define NC 256
#define QKV_STRIDE 16777216UL  // ushorts per tensor per batch (1024*8*64*32)

__device__ __forceinline__ unsigned short f2bf(float f) {
  union { float f; unsigned u; } v; v.f = f;
  unsigned r = v.u + 0x7FFFu + ((v.u >> 16) & 1u);  // RNE
  return (unsigned short)(r >> 16);
}

__global__ __launch_bounds__(256) void prep_weights(
    const float* __restrict__ wq, const float* __restrict__ wk,
    const float* __restrict__ wv, const float* __restrict__ wp,
    unsigned short* __restrict__ dst) {
  int i = blockIdx.x * 256 + threadIdx.x;  // 65536 elements
  dst[i]          = f2bf(wq[i]);
  dst[i + 65536]  = f2bf(wk[i]);
  dst[i + 131072] = f2bf(wv[i]);
  int e = i & 7, lane = (i >> 3) & 63, ks = (i >> 9) & 7, ot = i >> 12;
  int src = (ot * 16 + (lane & 15)) * 256 + ks * 32 + (lane >> 4) * 8 + e;
  dst[i + 196608] = f2bf(wp[src]);
}

// r2 staging: X[256 c][n0..n0+64) -> Xs[n][c] bf16, swz ((n&7)<<4)
__device__ __forceinline__ void stage_x(
    const float* __restrict__ x, int n0, int tid, unsigned char* __restrict__ smem) {
  const int sn = tid & 63;   // lane -> contiguous n (coalesced 256B/row)
  const int oc = tid >> 6;
#pragma unroll
  for (int it = 0; it < 8; ++it) {
    int c8 = (it * 4 + oc) * 8;
    const float* xp = x + (size_t)c8 * HW + n0 + sn;
    float v0 = xp[0],      v1 = xp[HW],     v2 = xp[2 * HW], v3 = xp[3 * HW];
    float v4 = xp[4 * HW], v5 = xp[5 * HW], v6 = xp[6 * HW], v7 = xp[7 * HW];
    uint4 u;
    u.x = (unsigned)f2bf(v0) | ((unsigned)f2bf(v1) << 16);
    u.y = (unsigned)f2bf(v2) | ((unsigned)f2bf(v3) << 16);
    u.z = (unsigned)f2bf(v4) | ((unsigned)f2bf(v5) << 16);
    u.w = (unsigned)f2bf(v6) | ((unsigned)f2bf(v7) << 16);
    unsigned byte = ((unsigned)(sn * 512 + c8 * 2)) ^ (((unsigned)(sn & 7)) << 4);
    *(uint4*)(smem + byte) = u;  // 16B write, conflict-free
  }
}

// r2 GEMM pass: acc = W[256x256] * Xs. W row-order; Xs as staged above.
__device__ __forceinline__ void gemm_pass(
    const unsigned short* __restrict__ wmat, const unsigned char* __restrict__ smem,
    int wid, int g, int qh, f32x4 (&acc)[4][4]) {
#pragma unroll
  for (int i = 0; i < 4; ++i)
#pragma unroll
    for (int j = 0; j < 4; ++j) acc[i][j] = (f32x4){0.f, 0.f, 0.f, 0.f};

  bfx8 afr[4];
#pragma unroll
  for (int mt = 0; mt < 4; ++mt)
    afr[mt] = *(const bfx8*)(wmat + (wid * 64 + mt * 16 + qh) * 256 + g * 8);

  for (int ks = 0; ks < 8; ++ks) {
    bfx8 naf[4];
    if (ks < 7) {
#pragma unroll
      for (int mt = 0; mt < 4; ++mt)
        naf[mt] = *(const bfx8*)(wmat + (wid * 64 + mt * 16 + qh) * 256 + (ks + 1) * 32 + g * 8);
    }
#pragma unroll
    for (int nt = 0; nt < 4; ++nt) {
      unsigned byte = ((unsigned)((nt * 16 + qh) * 512 + ks * 64 + g * 16)) ^
                      (((unsigned)(qh & 7)) << 4);
      bfx8 bfr = *(const bfx8*)(smem + byte);
#pragma unroll
      for (int mt = 0; mt < 4; ++mt)
        acc[mt][nt] = __builtin_amdgcn_mfma_f32_16x16x32_bf16(afr[mt], bfr, acc[mt][nt], 0, 0, 0);
    }
    if (ks < 7) {
#pragma unroll
      for (int mt = 0; mt < 4; ++mt) afr[mt] = naf[mt];
    }
  }
}

// Direct windowed store for Q/K layout [win*8+head][pos 64][d 32] (+bias).
__device__ __forceinline__ void store_qk(
    const f32x4 (&acc)[4][4], const float* __restrict__ bias,
    unsigned short* __restrict__ outw, int n0, int wid, int g, int qh) {
  const int h_img = n0 >> 8, w0b = n0 & 255;
#pragma unroll
  for (int mt = 0; mt < 4; ++mt) {
    int o = wid * 64 + mt * 16 + g * 4;
    f32x4 bb = *(const f32x4*)&bias[o];
    int head = o >> 5, dbase = o & 31;
#pragma unroll
    for (int nt = 0; nt < 4; ++nt) {
      int n = nt * 16 + qh;
      int w_img = w0b + n;
      int win = ((h_img >> 3) << 5) + (w_img >> 3);
      int pos = ((h_img & 7) << 3) + (w_img & 7);
      f32x4 a = acc[mt][nt];
      uint2 pv;
      pv.x = (unsigned)f2bf(a.x + bb.x) | ((unsigned)f2bf(a.y + bb.y) << 16);
      pv.y = (unsigned)f2bf(a.z + bb.z) | ((unsigned)f2bf(a.w + bb.w) << 16);
      *(uint2*)&outw[((size_t)(win * 8 + head) * 64 + pos) * 32 + dbase] = pv;
    }
  }
}

// ---------------- fused QKV projection GEMM ----------------
// grid (1024, 1, NB), 256 thr (4 waves). Block = one 64-pos tile, Q+K+V.
__global__ __launch_bounds__(256) void qkv_gemm(
    const float* __restrict__ xq, const float* __restrict__ xkv,
    const unsigned short* __restrict__ wbf,
    const float* __restrict__ bq, const float* __restrict__ bk,
    const float* __restrict__ bv,
    unsigned short* __restrict__ q_w, unsigned short* __restrict__ k_w,
    unsigned short* __restrict__ v_w, int batch0, int batched) {
  __shared__ __align__(16) unsigned char bufQ[32768];   // xq stage | V-epi
  __shared__ __align__(16) unsigned char bufKV[32768];  // xkv stage (K and V)

  const int tid = threadIdx.x;
  const int lane = tid & 63;
  const int wid = tid >> 6;
  const int g = lane >> 4;
  const int qh = lane & 15;
  const int n0 = (int)blockIdx.x * 64;
  const int batch = batch0 + blockIdx.z;
  const size_t qofs = batched ? (size_t)blockIdx.z * QKV_STRIDE : 0;
  const float* xq_b = xq + (size_t)batch * NC * HW;
  const float* xkv_b = xkv + (size_t)batch * NC * HW;

  // stage BOTH tensors: 128 loads in flight, one barrier
  stage_x(xq_b, n0, tid, bufQ);
  stage_x(xkv_b, n0, tid, bufKV);
  __syncthreads();

  f32x4 acc[4][4];
  gemm_pass(wbf, bufQ, wid, g, qh, acc);                 // wq
  store_qk(acc, bq, q_w + qofs, n0, wid, g, qh);
  gemm_pass(wbf + 65536, bufKV, wid, g, qh, acc);        // wk
  store_qk(acc, bk, k_w + qofs, n0, wid, g, qh);
  gemm_pass(wbf + 131072, bufKV, wid, g, qh, acc);       // wv

  __syncthreads();  // all LDS reads (incl. bufQ from Q pass) done
  // V epilogue transpose into bufQ: [o 256][n 64] bf16 (128B rows),
  // byte = o*128 + n*2 ^ (((o>>2)&7)<<4). Write conflicts <= 2-way (free).
#pragma unroll
  for (int mt = 0; mt < 4; ++mt) {
    int o = wid * 64 + mt * 16 + g * 4;
    f32x4 bb = *(const f32x4*)&bv[o];
#pragma unroll
    for (int nt = 0; nt < 4; ++nt) {
      int n = nt * 16 + qh;
      f32x4 a = acc[mt][nt];
      float vj[4] = {a.x + bb.x, a.y + bb.y, a.z + bb.z, a.w + bb.w};
#pragma unroll
      for (int j = 0; j < 4; ++j) {
        unsigned oo = (unsigned)(o + j);
        unsigned byte = (oo * 128 + (unsigned)n * 2) ^ (((oo >> 2) & 7u) << 4);
        *(unsigned short*)(bufQ + byte) = f2bf(vj[j]);
      }
    }
  }
  __syncthreads();
  // V store: NEW layout [win*8+head][rowblk 8][d 32][col 8].
  // Block owns rowblk = h_img&7 -> 512B contiguous per (win,head):
  // per instruction 8 x 128B FULL lines (no cross-block line assembly).
  const int h_img = n0 >> 8, w0b = n0 & 255;
  const int h7 = h_img & 7;
  unsigned short* vw = v_w + qofs;
#pragma unroll
  for (int it = 0; it < 8; ++it) {
    int id = it * 256 + tid;
    unsigned o = (unsigned)(id >> 3);   // channel 0..255
    int oct = id & 7;                   // window octet within tile
    unsigned byte = (o * 128 + (unsigned)oct * 16) ^ (((o >> 2) & 7u) << 4);
    uint4 val = *(const uint4*)(bufQ + byte);  // Vt[o][cols oct*8..+8]
    int head = (int)(o >> 5), dd = (int)(o & 31);
    int win = ((h_img >> 3) << 5) + (w0b >> 3) + oct;
    *(uint4*)&vw[(size_t)(win * 8 + head) * 2048 + (size_t)(h7 * 256 + dd * 8)] = val;
  }
}

// ---------------- fused windowed attention + output conv ----------------
// Block: 256 thr (4 waves) = 1 window. Wave handles heads {wid, wid+4}.
__global__ __launch_bounds__(256) void attn_conv(
    const unsigned short* __restrict__ q_w, const unsigned short* __restrict__ k_w,
    const unsigned short* __restrict__ v_w, const unsigned short* __restrict__ wpT,
    const float* __restrict__ bp, float* __restrict__ out, int batch0, int batched) {
  __shared__ unsigned short P_lds[4][2048];  // per-wave P half-tile [64 q][32 k], swizzled
  __shared__ unsigned short y_t[16384];      // [pos 64][c 256] bf16, swizzled

  const int tid = threadIdx.x;
  const int lane = tid & 63;
  const int wid = tid >> 6;
  const int g = lane >> 4;
  const int qh = lane & 15;
  const int bid = blockIdx.x;
  // XCD-chunked swizzle: XCD j owns winl [j*128, +128).
  const int winl = ((bid & 7) << 7) | (bid >> 3);
  const int batch = batch0 + blockIdx.z;
  const size_t qofs = batched ? (size_t)blockIdx.z * QKV_STRIDE : 0;
  const float scale = 0.17677669529663687f;  // 1/sqrt(32)

  char* pbase = (char*)&P_lds[wid][0];

#pragma unroll
  for (int hi = 0; hi < 2; ++hi) {
    const int head = wid + hi * 4;
    const unsigned short* qb = q_w + qofs + (size_t)(winl * 8 + head) * 2048;
    const unsigned short* kb = k_w + qofs + (size_t)(winl * 8 + head) * 2048;
    const unsigned short* vb = v_w + qofs + (size_t)(winl * 8 + head) * 2048;

    bfx8 kf[4], qf[4];
#pragma unroll
    for (int t = 0; t < 4; ++t) {
      kf[t] = *(const bfx8*)(kb + (t * 16 + qh) * 32 + g * 8);
      qf[t] = *(const bfx8*)(qb + (t * 16 + qh) * 32 + g * 8);
    }
    // S^T[kpos][q] = sum_d K[kpos][d] * Q[q][d]
    f32x4 zero = {0.f, 0.f, 0.f, 0.f};
    f32x4 st[4][4];
#pragma unroll
    for (int kt = 0; kt < 4; ++kt)
#pragma unroll
      for (int qt = 0; qt < 4; ++qt)
        st[kt][qt] = __builtin_amdgcn_mfma_f32_16x16x32_bf16(kf[kt], qf[qt], zero, 0, 0, 0);

    // softmax over kpos (rows of S^T)
    float rv[4];
#pragma unroll
    for (int qt = 0; qt < 4; ++qt) {
      float m = -1e30f;
#pragma unroll
      for (int kt = 0; kt < 4; ++kt) {
        f32x4 v = st[kt][qt];
        m = fmaxf(m, fmaxf(fmaxf(v.x, v.y), fmaxf(v.z, v.w)));
      }
      m = fmaxf(m, __shfl_xor(m, 16, 64));
      m = fmaxf(m, __shfl_xor(m, 32, 64));
      float ssum = 0.f;
#pragma unroll
      for (int kt = 0; kt < 4; ++kt) {
        f32x4 v = st[kt][qt], e;
        e.x = __expf((v.x - m) * scale);
        e.y = __expf((v.y - m) * scale);
        e.z = __expf((v.z - m) * scale);
        e.w = __expf((v.w - m) * scale);
        ssum += e.x + e.y + e.z + e.w;
        st[kt][qt] = e;
      }
      ssum += __shfl_xor(ssum, 16, 64);
      ssum += __shfl_xor(ssum, 32, 64);
      rv[qt] = 1.f / ssum;
    }

    // PV: out^T[d][q] = sum_k V^T[d][k] * P
    f32x4 ot[2][4];
#pragma unroll
    for (int dt = 0; dt < 2; ++dt)
#pragma unroll
      for (int qt = 0; qt < 4; ++qt) ot[dt][qt] = zero;

#pragma unroll
    for (int s = 0; s < 2; ++s) {
#pragma unroll
      for (int qt = 0; qt < 4; ++qt) {
        int q = qt * 16 + qh;
        unsigned sw = ((unsigned)(q & 3)) << 4;
        float r = rv[qt];
#pragma unroll
        for (int k2 = 0; k2 < 2; ++k2) {
          f32x4 e = st[s * 2 + k2][qt];
          uint2 pv;
          pv.x = (unsigned)f2bf(e.x * r) | ((unsigned)f2bf(e.y * r) << 16);
          pv.y = (unsigned)f2bf(e.z * r) | ((unsigned)f2bf(e.w * r) << 16);
          unsigned byte = ((unsigned)q * 64 + (unsigned)(k2 * 32 + g * 8)) ^ sw;
          *(uint2*)(pbase + byte) = pv;
        }
      }
      bfx8 pf[4];
#pragma unroll
      for (int qt = 0; qt < 4; ++qt) {
        int q = qt * 16 + qh;
        unsigned byte = ((unsigned)q * 64 + (unsigned)(g * 16)) ^ (((unsigned)(q & 3)) << 4);
        pf[qt] = *(const bfx8*)(pbase + byte);
      }
#pragma unroll
      for (int dt = 0; dt < 2; ++dt) {
        // V layout [rowblk 8][d 32][col 8]: pos-run s*32+g*8 -> rowblk s*4+g
        bfx8 vf = *(const bfx8*)(vb + (s * 4 + g) * 256 + (dt * 16 + qh) * 8);
#pragma unroll
        for (int qt = 0; qt < 4; ++qt)
          ot[dt][qt] = __builtin_amdgcn_mfma_f32_16x16x32_bf16(vf, pf[qt], ot[dt][qt], 0, 0, 0);
      }
    }

    // attention output -> y_t[pos][c] (swizzled), c = head*32 + d
#pragma unroll
    for (int dt = 0; dt < 2; ++dt) {
      int cb = head * 32 + dt * 16 + g * 4;
#pragma unroll
      for (int qt = 0; qt < 4; ++qt) {
        int pos = qt * 16 + qh;
        f32x4 a = ot[dt][qt];
        uint2 pv;
        pv.x = (unsigned)f2bf(a.x) | ((unsigned)f2bf(a.y) << 16);
        pv.y = (unsigned)f2bf(a.z) | ((unsigned)f2bf(a.w) << 16);
        unsigned byte = ((unsigned)pos * 512 + (unsigned)cb * 2) ^ (((unsigned)(pos & 7)) << 4);
        *(uint2*)((char*)y_t + byte) = pv;
      }
    }
  }
  __syncthreads();

  // output conv: out[o][pos] = sum_c wp[o][c] * y[c][pos]; wave wid: o in [64*wid, +64)
  f32x4 acc[4][4];
#pragma unroll
  for (int i = 0; i < 4; ++i)
#pragma unroll
    for (int j = 0; j < 4; ++j) acc[i][j] = (f32x4){0.f, 0.f, 0.f, 0.f};

  for (int ks = 0; ks < 8; ++ks) {
    bfx8 af[4];
#pragma unroll
    for (int mt = 0; mt < 4; ++mt)
      af[mt] = *(const bfx8*)(wpT + (((wid * 4 + mt) * 8 + ks) * 64 + lane) * 8);
#pragma unroll
    for (int nt = 0; nt < 4; ++nt) {
      int pos = nt * 16 + qh;
      unsigned byte = ((unsigned)pos * 512 + (unsigned)(ks * 64 + g * 16)) ^ (((unsigned)(pos & 7)) << 4);
      bfx8 bfr = *(const bfx8*)((char*)y_t + byte);
#pragma unroll
      for (int mt = 0; mt < 4; ++mt)
        acc[mt][nt] = __builtin_amdgcn_mfma_f32_16x16x32_bf16(af[mt], bfr, acc[mt][nt], 0, 0, 0);
    }
  }

  const int wrow = winl >> 5, wcol = winl & 31;
  float* ob_ = out + (size_t)batch * NC * HW;
#pragma unroll
  for (int mt = 0; mt < 4; ++mt) {
    int o0 = wid * 64 + mt * 16 + g * 4;
    float b0 = bp[o0], b1 = bp[o0 + 1], b2 = bp[o0 + 2], b3 = bp[o0 + 3];
#pragma unroll
    for (int nt = 0; nt < 4; ++nt) {
      int pos = nt * 16 + qh;
      int h_img = wrow * 8 + (pos >> 3);
      int w_img = wcol * 8 + (pos & 7);
      float* pp = ob_ + (size_t)o0 * HW + h_img * 256 + w_img;
      pp[0]      = acc[mt][nt].x + b0;
      pp[HW]     = acc[mt][nt].y + b1;
      pp[2 * HW] = acc[mt][nt].z + b2;
      pp[3 * HW] = acc[mt][nt].w + b3;
    }
  }
}

extern "C" void kernel_launch(void* const* d_in, const int* in_sizes, int n_in,
                              void* d_out, int out_size, void* d_ws, size_t ws_size,
                              hipStream_t stream) {
  const float* q_feat = (const float*)d_in[0];
  const float* kv_feat = (const float*)d_in[1];
  const float* wq = (const float*)d_in[2];
  const float* bq = (const float*)d_in[3];
  const float* wk = (const float*)d_in[4];
  const float* bk = (const float*)d_in[5];
  const float* wv = (const float*)d_in[6];
  const float* bv = (const float*)d_in[7];
  const float* wp = (const float*)d_in[8];
  const float* bp = (const float*)d_in[9];
  float* out = (float*)d_out;

  unsigned short* wbf = (unsigned short*)d_ws;  // 4 x 65536 bf16 = 512 KB
  const size_t need_batched = 524288ul + 12ul * QKV_STRIDE * 2ul;  // ~403 MB

  hipLaunchKernelGGL(prep_weights, dim3(256), dim3(256), 0, stream, wq, wk, wv, wp, wbf);

  if (ws_size >= need_batched) {
    // all-batch path: 2 big launches
    unsigned short* q_w = wbf + 262144;
    unsigned short* k_w = q_w + 4 * QKV_STRIDE;
    unsigned short* v_w = k_w + 4 * QKV_STRIDE;
    hipLaunchKernelGGL(qkv_gemm, dim3(1024, 1, 4), dim3(256), 0, stream,
                       q_feat, kv_feat, wbf, bq, bk, bv, q_w, k_w, v_w, 0, 1);
    hipLaunchKernelGGL(attn_conv, dim3(1024, 1, 4), dim3(256), 0, stream,
                       q_w, k_w, v_w, wbf + 196608, bp, out, 0, 1);
  } else {
    // per-batch fallback (~97 MB workspace)
    unsigned short* q_w = wbf + 262144;
    unsigned short* k_w = q_w + QKV_STRIDE;
    unsigned short* v_w = k_w + QKV_STRIDE;
    for (int b = 0; b < 4; ++b) {
      hipLaunchKernelGGL(qkv_gemm, dim3(1024, 1, 1), dim3(256), 0, stream,
                         q_feat, kv_feat, wbf, bq, bk, bv, q_w, k_w, v_w, b, 0);
      hipLaunchKernelGGL(attn_conv, dim3(1024, 1, 1), dim3(256), 0, stream,
                         q_w, k_w, v_w, wbf + 196608, bp, out, b, 0);
    }
  }
}

// Round 12
// 535.466 us; speedup vs baseline: 1.8612x; 1.0527x over previous
//
#include <hip/hip_runtime.h>
#include <cstdint>
#include <cstddef>

// SAMGuidedCrossAttention: B=4, C=256, H=W=256, heads=8, ws=8, d=32
// Round 12 = r11 fused-QKV + full-line V layout, re-shaped to 512-thr/8-wave
// blocks (same tile, same 64KB LDS -> still 2 blocks/CU, but 16 waves/CU
// instead of 8). qkv is at its ACHIEVED-BW limit (667MB @ 1.67TB/s = dur);
// bytes are ideal, so the lever is concurrency: 2x resident waves = 2x
// outstanding loads/stores (Little's law) -> higher achieved BW.
//   qkv_gemm: 512 thr. Wave ow=wid owns M=32 rows; acc[2][4]=32 VGPR
//     (~90 total, no spill; __launch_bounds__(512) WITHOUT min-waves to
//     avoid the r6 allocator clamp). Stage 32 loads/thread/tensor.
//   attn_conv: r11 unchanged (XCD swizzle, wpT frags, [rowblk][d][col] V).

typedef __attribute__((ext_vector_type(8))) short bfx8;   // 8 bf16 (4 VGPR)
typedef __attribute__((ext_vector_type(4))) float f32x4;  // MFMA acc

#define HW 65536
#define NC 256
#define QKV_STRIDE 16777216UL  // ushorts per tensor per batch (1024*8*64*32)

__device__ __forceinline__ unsigned short f2bf(float f) {
  union { float f; unsigned u; } v; v.f = f;
  unsigned r = v.u + 0x7FFFu + ((v.u >> 16) & 1u);  // RNE
  return (unsigned short)(r >> 16);
}

__global__ __launch_bounds__(256) void prep_weights(
    const float* __restrict__ wq, const float* __restrict__ wk,
    const float* __restrict__ wv, const float* __restrict__ wp,
    unsigned short* __restrict__ dst) {
  int i = blockIdx.x * 256 + threadIdx.x;  // 65536 elements
  dst[i]          = f2bf(wq[i]);
  dst[i + 65536]  = f2bf(wk[i]);
  dst[i + 131072] = f2bf(wv[i]);
  int e = i & 7, lane = (i >> 3) & 63, ks = (i >> 9) & 7, ot = i >> 12;
  int src = (ot * 16 + (lane & 15)) * 256 + ks * 32 + (lane >> 4) * 8 + e;
  dst[i + 196608] = f2bf(wp[src]);
}

// staging (512 thr): X[256 c][n0..n0+64) -> Xs[n][c] bf16, swz ((n&7)<<4)
__device__ __forceinline__ void stage_x512(
    const float* __restrict__ x, int n0, int tid, unsigned char* __restrict__ smem) {
  const int sn = tid & 63;   // lane -> contiguous n (coalesced 256B/row)
  const int oc = tid >> 6;   // 0..7
#pragma unroll
  for (int it = 0; it < 4; ++it) {
    int c8 = (it * 8 + oc) * 8;   // channel base, multiples of 8
    const float* xp = x + (size_t)c8 * HW + n0 + sn;
    float v0 = xp[0],      v1 = xp[HW],     v2 = xp[2 * HW], v3 = xp[3 * HW];
    float v4 = xp[4 * HW], v5 = xp[5 * HW], v6 = xp[6 * HW], v7 = xp[7 * HW];
    uint4 u;
    u.x = (unsigned)f2bf(v0) | ((unsigned)f2bf(v1) << 16);
    u.y = (unsigned)f2bf(v2) | ((unsigned)f2bf(v3) << 16);
    u.z = (unsigned)f2bf(v4) | ((unsigned)f2bf(v5) << 16);
    u.w = (unsigned)f2bf(v6) | ((unsigned)f2bf(v7) << 16);
    unsigned byte = ((unsigned)(sn * 512 + c8 * 2)) ^ (((unsigned)(sn & 7)) << 4);
    *(uint4*)(smem + byte) = u;  // 16B write, conflict-free
  }
}

// GEMM pass (8 waves): wave ow owns rows [ow*32, +32); N = all 64.
__device__ __forceinline__ void gemm_pass512(
    const unsigned short* __restrict__ wmat, const unsigned char* __restrict__ smem,
    int ow, int g, int qh, f32x4 (&acc)[2][4]) {
#pragma unroll
  for (int i = 0; i < 2; ++i)
#pragma unroll
    for (int j = 0; j < 4; ++j) acc[i][j] = (f32x4){0.f, 0.f, 0.f, 0.f};

  bfx8 afr[2];
#pragma unroll
  for (int mt = 0; mt < 2; ++mt)
    afr[mt] = *(const bfx8*)(wmat + (ow * 32 + mt * 16 + qh) * 256 + g * 8);

  for (int ks = 0; ks < 8; ++ks) {
    bfx8 naf[2];
    if (ks < 7) {
#pragma unroll
      for (int mt = 0; mt < 2; ++mt)
        naf[mt] = *(const bfx8*)(wmat + (ow * 32 + mt * 16 + qh) * 256 + (ks + 1) * 32 + g * 8);
    }
#pragma unroll
    for (int nt = 0; nt < 4; ++nt) {
      unsigned byte = ((unsigned)((nt * 16 + qh) * 512 + ks * 64 + g * 16)) ^
                      (((unsigned)(qh & 7)) << 4);
      bfx8 bfr = *(const bfx8*)(smem + byte);
#pragma unroll
      for (int mt = 0; mt < 2; ++mt)
        acc[mt][nt] = __builtin_amdgcn_mfma_f32_16x16x32_bf16(afr[mt], bfr, acc[mt][nt], 0, 0, 0);
    }
    if (ks < 7) { afr[0] = naf[0]; afr[1] = naf[1]; }
  }
}

// Direct windowed store for Q/K layout [win*8+head][pos 64][d 32] (+bias).
__device__ __forceinline__ void store_qk512(
    const f32x4 (&acc)[2][4], const float* __restrict__ bias,
    unsigned short* __restrict__ outw, int n0, int ow, int g, int qh) {
  const int h_img = n0 >> 8, w0b = n0 & 255;
#pragma unroll
  for (int mt = 0; mt < 2; ++mt) {
    int o = ow * 32 + mt * 16 + g * 4;
    f32x4 bb = *(const f32x4*)&bias[o];
    int head = o >> 5, dbase = o & 31;
#pragma unroll
    for (int nt = 0; nt < 4; ++nt) {
      int n = nt * 16 + qh;
      int w_img = w0b + n;
      int win = ((h_img >> 3) << 5) + (w_img >> 3);
      int pos = ((h_img & 7) << 3) + (w_img & 7);
      f32x4 a = acc[mt][nt];
      uint2 pv;
      pv.x = (unsigned)f2bf(a.x + bb.x) | ((unsigned)f2bf(a.y + bb.y) << 16);
      pv.y = (unsigned)f2bf(a.z + bb.z) | ((unsigned)f2bf(a.w + bb.w) << 16);
      *(uint2*)&outw[((size_t)(win * 8 + head) * 64 + pos) * 32 + dbase] = pv;
    }
  }
}

// ---------------- fused QKV projection GEMM ----------------
// grid (1024, 1, NB), 512 thr (8 waves). Block = one 64-pos tile, Q+K+V.
__global__ __launch_bounds__(512) void qkv_gemm(
    const float* __restrict__ xq, const float* __restrict__ xkv,
    const unsigned short* __restrict__ wbf,
    const float* __restrict__ bq, const float* __restrict__ bk,
    const float* __restrict__ bv,
    unsigned short* __restrict__ q_w, unsigned short* __restrict__ k_w,
    unsigned short* __restrict__ v_w, int batch0, int batched) {
  __shared__ __align__(16) unsigned char bufQ[32768];   // xq stage | V-epi
  __shared__ __align__(16) unsigned char bufKV[32768];  // xkv stage (K and V)

  const int tid = threadIdx.x;
  const int lane = tid & 63;
  const int wid = tid >> 6;        // 0..7 = ow
  const int g = lane >> 4;
  const int qh = lane & 15;
  const int n0 = (int)blockIdx.x * 64;
  const int batch = batch0 + blockIdx.z;
  const size_t qofs = batched ? (size_t)blockIdx.z * QKV_STRIDE : 0;
  const float* xq_b = xq + (size_t)batch * NC * HW;
  const float* xkv_b = xkv + (size_t)batch * NC * HW;

  // stage BOTH tensors: all loads in flight, one barrier
  stage_x512(xq_b, n0, tid, bufQ);
  stage_x512(xkv_b, n0, tid, bufKV);
  __syncthreads();

  f32x4 acc[2][4];
  gemm_pass512(wbf, bufQ, wid, g, qh, acc);              // wq
  store_qk512(acc, bq, q_w + qofs, n0, wid, g, qh);
  gemm_pass512(wbf + 65536, bufKV, wid, g, qh, acc);     // wk
  store_qk512(acc, bk, k_w + qofs, n0, wid, g, qh);
  gemm_pass512(wbf + 131072, bufKV, wid, g, qh, acc);    // wv

  __syncthreads();  // all LDS reads (incl. bufQ from Q pass) done
  // V epilogue transpose into bufQ: [o 256][n 64] bf16 (128B rows),
  // byte = o*128 + n*2 ^ (((o>>2)&7)<<4). Conflicts <= 2-way (free).
#pragma unroll
  for (int mt = 0; mt < 2; ++mt) {
    int o = wid * 32 + mt * 16 + g * 4;
    f32x4 bb = *(const f32x4*)&bv[o];
#pragma unroll
    for (int nt = 0; nt < 4; ++nt) {
      int n = nt * 16 + qh;
      f32x4 a = acc[mt][nt];
      float vj[4] = {a.x + bb.x, a.y + bb.y, a.z + bb.z, a.w + bb.w};
#pragma unroll
      for (int j = 0; j < 4; ++j) {
        unsigned oo = (unsigned)(o + j);
        unsigned byte = (oo * 128 + (unsigned)n * 2) ^ (((oo >> 2) & 7u) << 4);
        *(unsigned short*)(bufQ + byte) = f2bf(vj[j]);
      }
    }
  }
  __syncthreads();
  // V store: [win*8+head][rowblk 8][d 32][col 8] -> 512B contiguous per
  // (win,head), 8x128B FULL lines per instruction (r11 proven layout).
  const int h_img = n0 >> 8, w0b = n0 & 255;
  const int h7 = h_img & 7;
  unsigned short* vw = v_w + qofs;
#pragma unroll
  for (int it = 0; it < 4; ++it) {
    int id = it * 512 + tid;
    unsigned o = (unsigned)(id >> 3);   // channel 0..255
    int oct = id & 7;                   // window octet within tile
    unsigned byte = (o * 128 + (unsigned)oct * 16) ^ (((o >> 2) & 7u) << 4);
    uint4 val = *(const uint4*)(bufQ + byte);  // Vt[o][cols oct*8..+8]
    int head = (int)(o >> 5), dd = (int)(o & 31);
    int win = ((h_img >> 3) << 5) + (w0b >> 3) + oct;
    *(uint4*)&vw[(size_t)(win * 8 + head) * 2048 + (size_t)(h7 * 256 + dd * 8)] = val;
  }
}

// ---------------- fused windowed attention + output conv ----------------
// Block: 256 thr (4 waves) = 1 window. Wave handles heads {wid, wid+4}.
__global__ __launch_bounds__(256) void attn_conv(
    const unsigned short* __restrict__ q_w, const unsigned short* __restrict__ k_w,
    const unsigned short* __restrict__ v_w, const unsigned short* __restrict__ wpT,
    const float* __restrict__ bp, float* __restrict__ out, int batch0, int batched) {
  __shared__ unsigned short P_lds[4][2048];  // per-wave P half-tile [64 q][32 k], swizzled
  __shared__ unsigned short y_t[16384];      // [pos 64][c 256] bf16, swizzled

  const int tid = threadIdx.x;
  const int lane = tid & 63;
  const int wid = tid >> 6;
  const int g = lane >> 4;
  const int qh = lane & 15;
  const int bid = blockIdx.x;
  // XCD-chunked swizzle: XCD j owns winl [j*128, +128).
  const int winl = ((bid & 7) << 7) | (bid >> 3);
  const int batch = batch0 + blockIdx.z;
  const size_t qofs = batched ? (size_t)blockIdx.z * QKV_STRIDE : 0;
  const float scale = 0.17677669529663687f;  // 1/sqrt(32)

  char* pbase = (char*)&P_lds[wid][0];

#pragma unroll
  for (int hi = 0; hi < 2; ++hi) {
    const int head = wid + hi * 4;
    const unsigned short* qb = q_w + qofs + (size_t)(winl * 8 + head) * 2048;
    const unsigned short* kb = k_w + qofs + (size_t)(winl * 8 + head) * 2048;
    const unsigned short* vb = v_w + qofs + (size_t)(winl * 8 + head) * 2048;

    bfx8 kf[4], qf[4];
#pragma unroll
    for (int t = 0; t < 4; ++t) {
      kf[t] = *(const bfx8*)(kb + (t * 16 + qh) * 32 + g * 8);
      qf[t] = *(const bfx8*)(qb + (t * 16 + qh) * 32 + g * 8);
    }
    // S^T[kpos][q] = sum_d K[kpos][d] * Q[q][d]
    f32x4 zero = {0.f, 0.f, 0.f, 0.f};
    f32x4 st[4][4];
#pragma unroll
    for (int kt = 0; kt < 4; ++kt)
#pragma unroll
      for (int qt = 0; qt < 4; ++qt)
        st[kt][qt] = __builtin_amdgcn_mfma_f32_16x16x32_bf16(kf[kt], qf[qt], zero, 0, 0, 0);

    // softmax over kpos (rows of S^T)
    float rv[4];
#pragma unroll
    for (int qt = 0; qt < 4; ++qt) {
      float m = -1e30f;
#pragma unroll
      for (int kt = 0; kt < 4; ++kt) {
        f32x4 v = st[kt][qt];
        m = fmaxf(m, fmaxf(fmaxf(v.x, v.y), fmaxf(v.z, v.w)));
      }
      m = fmaxf(m, __shfl_xor(m, 16, 64));
      m = fmaxf(m, __shfl_xor(m, 32, 64));
      float ssum = 0.f;
#pragma unroll
      for (int kt = 0; kt < 4; ++kt) {
        f32x4 v = st[kt][qt], e;
        e.x = __expf((v.x - m) * scale);
        e.y = __expf((v.y - m) * scale);
        e.z = __expf((v.z - m) * scale);
        e.w = __expf((v.w - m) * scale);
        ssum += e.x + e.y + e.z + e.w;
        st[kt][qt] = e;
      }
      ssum += __shfl_xor(ssum, 16, 64);
      ssum += __shfl_xor(ssum, 32, 64);
      rv[qt] = 1.f / ssum;
    }

    // PV: out^T[d][q] = sum_k V^T[d][k] * P
    f32x4 ot[2][4];
#pragma unroll
    for (int dt = 0; dt < 2; ++dt)
#pragma unroll
      for (int qt = 0; qt < 4; ++qt) ot[dt][qt] = zero;

#pragma unroll
    for (int s = 0; s < 2; ++s) {
#pragma unroll
      for (int qt = 0; qt < 4; ++qt) {
        int q = qt * 16 + qh;
        unsigned sw = ((unsigned)(q & 3)) << 4;
        float r = rv[qt];
#pragma unroll
        for (int k2 = 0; k2 < 2; ++k2) {
          f32x4 e = st[s * 2 + k2][qt];
          uint2 pv;
          pv.x = (unsigned)f2bf(e.x * r) | ((unsigned)f2bf(e.y * r) << 16);
          pv.y = (unsigned)f2bf(e.z * r) | ((unsigned)f2bf(e.w * r) << 16);
          unsigned byte = ((unsigned)q * 64 + (unsigned)(k2 * 32 + g * 8)) ^ sw;
          *(uint2*)(pbase + byte) = pv;
        }
      }
      bfx8 pf[4];
#pragma unroll
      for (int qt = 0; qt < 4; ++qt) {
        int q = qt * 16 + qh;
        unsigned byte = ((unsigned)q * 64 + (unsigned)(g * 16)) ^ (((unsigned)(q & 3)) << 4);
        pf[qt] = *(const bfx8*)(pbase + byte);
      }
#pragma unroll
      for (int dt = 0; dt < 2; ++dt) {
        // V layout [rowblk 8][d 32][col 8]: pos-run s*32+g*8 -> rowblk s*4+g
        bfx8 vf = *(const bfx8*)(vb + (s * 4 + g) * 256 + (dt * 16 + qh) * 8);
#pragma unroll
        for (int qt = 0; qt < 4; ++qt)
          ot[dt][qt] = __builtin_amdgcn_mfma_f32_16x16x32_bf16(vf, pf[qt], ot[dt][qt], 0, 0, 0);
      }
    }

    // attention output -> y_t[pos][c] (swizzled), c = head*32 + d
#pragma unroll
    for (int dt = 0; dt < 2; ++dt) {
      int cb = head * 32 + dt * 16 + g * 4;
#pragma unroll
      for (int qt = 0; qt < 4; ++qt) {
        int pos = qt * 16 + qh;
        f32x4 a = ot[dt][qt];
        uint2 pv;
        pv.x = (unsigned)f2bf(a.x) | ((unsigned)f2bf(a.y) << 16);
        pv.y = (unsigned)f2bf(a.z) | ((unsigned)f2bf(a.w) << 16);
        unsigned byte = ((unsigned)pos * 512 + (unsigned)cb * 2) ^ (((unsigned)(pos & 7)) << 4);
        *(uint2*)((char*)y_t + byte) = pv;
      }
    }
  }
  __syncthreads();

  // output conv: out[o][pos] = sum_c wp[o][c] * y[c][pos]; wave wid: o in [64*wid, +64)
  f32x4 acc[4][4];
#pragma unroll
  for (int i = 0; i < 4; ++i)
#pragma unroll
    for (int j = 0; j < 4; ++j) acc[i][j] = (f32x4){0.f, 0.f, 0.f, 0.f};

  for (int ks = 0; ks < 8; ++ks) {
    bfx8 af[4];
#pragma unroll
    for (int mt = 0; mt < 4; ++mt)
      af[mt] = *(const bfx8*)(wpT + (((wid * 4 + mt) * 8 + ks) * 64 + lane) * 8);
#pragma unroll
    for (int nt = 0; nt < 4; ++nt) {
      int pos = nt * 16 + qh;
      unsigned byte = ((unsigned)pos * 512 + (unsigned)(ks * 64 + g * 16)) ^ (((unsigned)(pos & 7)) << 4);
      bfx8 bfr = *(const bfx8*)((char*)y_t + byte);
#pragma unroll
      for (int mt = 0; mt < 4; ++mt)
        acc[mt][nt] = __builtin_amdgcn_mfma_f32_16x16x32_bf16(af[mt], bfr, acc[mt][nt], 0, 0, 0);
    }
  }

  const int wrow = winl >> 5, wcol = winl & 31;
  float* ob_ = out + (size_t)batch * NC * HW;
#pragma unroll
  for (int mt = 0; mt < 4; ++mt) {
    int o0 = wid * 64 + mt * 16 + g * 4;
    float b0 = bp[o0], b1 = bp[o0 + 1], b2 = bp[o0 + 2], b3 = bp[o0 + 3];
#pragma unroll
    for (int nt = 0; nt < 4; ++nt) {
      int pos = nt * 16 + qh;
      int h_img = wrow * 8 + (pos >> 3);
      int w_img = wcol * 8 + (pos & 7);
      float* pp = ob_ + (size_t)o0 * HW + h_img * 256 + w_img;
      pp[0]      = acc[mt][nt].x + b0;
      pp[HW]     = acc[mt][nt].y + b1;
      pp[2 * HW] = acc[mt][nt].z + b2;
      pp[3 * HW] = acc[mt][nt].w + b3;
    }
  }
}

extern "C" void kernel_launch(void* const* d_in, const int* in_sizes, int n_in,
                              void* d_out, int out_size, void* d_ws, size_t ws_size,
                              hipStream_t stream) {
  const float* q_feat = (const float*)d_in[0];
  const float* kv_feat = (const float*)d_in[1];
  const float* wq = (const float*)d_in[2];
  const float* bq = (const float*)d_in[3];
  const float* wk = (const float*)d_in[4];
  const float* bk = (const float*)d_in[5];
  const float* wv = (const float*)d_in[6];
  const float* bv = (const float*)d_in[7];
  const float* wp = (const float*)d_in[8];
  const float* bp = (const float*)d_in[9];
  float* out = (float*)d_out;

  unsigned short* wbf = (unsigned short*)d_ws;  // 4 x 65536 bf16 = 512 KB
  const size_t need_batched = 524288ul + 12ul * QKV_STRIDE * 2ul;  // ~403 MB

  hipLaunchKernelGGL(prep_weights, dim3(256), dim3(256), 0, stream, wq, wk, wv, wp, wbf);

  if (ws_size >= need_batched) {
    // all-batch path: 2 big launches
    unsigned short* q_w = wbf + 262144;
    unsigned short* k_w = q_w + 4 * QKV_STRIDE;
    unsigned short* v_w = k_w + 4 * QKV_STRIDE;
    hipLaunchKernelGGL(qkv_gemm, dim3(1024, 1, 4), dim3(512), 0, stream,
                       q_feat, kv_feat, wbf, bq, bk, bv, q_w, k_w, v_w, 0, 1);
    hipLaunchKernelGGL(attn_conv, dim3(1024, 1, 4), dim3(256), 0, stream,
                       q_w, k_w, v_w, wbf + 196608, bp, out, 0, 1);
  } else {
    // per-batch fallback (~97 MB workspace)
    unsigned short* q_w = wbf + 262144;
    unsigned short* k_w = q_w + QKV_STRIDE;
    unsigned short* v_w = k_w + QKV_STRIDE;
    for (int b = 0; b < 4; ++b) {
      hipLaunchKernelGGL(qkv_gemm, dim3(1024, 1, 1), dim3(512), 0, stream,
                         q_feat, kv_feat, wbf, bq, bk, bv, q_w, k_w, v_w, b, 0);
      hipLaunchKernelGGL(attn_conv, dim3(1024, 1, 1), dim3(256), 0, stream,
                         q_w, k_w, v_w, wbf + 196608, bp, out, b, 0);
    }
  }
}